// Round 3
// baseline (44312.817 us; speedup 1.0000x reference)
//
#include <hip/hip_runtime.h>
#include <cstdint>
#include <cstddef>

#define FEAT 256
#define HWPX 16384
#define NDIR 10000
#define NCLS 4          // classes 1..4
#define BCAP 4096       // per-class column capacity for B (n_c ~ 3277)
#define NSWEEP 12       // max sweeps; early-exit on zero-rotation sweep (typ ~6-7)
#define JTOL 4e-12f     // skip rotation if d^2 <= |p|^2|q|^2 * JTOL  (|d| <= 2e-6*|p||q|)
#define NBLK_FP 157     // ceil(NDIR/64)

// ---- workspace layout (element offsets; 4B elements) ----
static const size_t OFF_FEATT = 0;                                // 16384*256 f32
static const size_t OFF_IDX   = OFF_FEATT + (size_t)HWPX*FEAT;    // 4*16384 int
static const size_t OFF_CNT   = OFF_IDX + (size_t)NCLS*HWPX;      // 4 int (+pad)
static const size_t OFF_MIU   = OFF_CNT + 64;                     // 4*256 f32
static const size_t OFF_MIUP  = OFF_MIU + (size_t)NCLS*FEAT;      // 32*4*256 f32 partials
static const size_t OFF_G     = OFF_MIUP + (size_t)32*NCLS*FEAT;  // 4*65536 f32
static const size_t OFF_ETS   = OFF_G + (size_t)NCLS*FEAT*FEAT;   // 4*65536 f32
static const size_t OFF_EVAL  = OFF_ETS + (size_t)NCLS*FEAT*FEAT; // 4*256 f32
static const size_t OFF_LPART = OFF_EVAL + (size_t)NCLS*FEAT;     // 4*160*2 f32 per-block partials
static const size_t OFF_B     = OFF_LPART + (size_t)NCLS*160*2;   // 4*256*BCAP f32

__device__ __forceinline__ float f4c(const float4& v, int j){
  return (j==0)? v.x : (j==1)? v.y : (j==2)? v.z : v.w;
}

// ---------------- transpose feat (256 x 16384) -> featT (16384 x 256) ----------------
__global__ __launch_bounds__(256) void k_transpose(const float* __restrict__ feat, float* __restrict__ ws){
  __shared__ float tile[32][33];
  float* featT = ws + OFF_FEATT;
  int j0 = blockIdx.x*32, f0 = blockIdx.y*32;
  int tx = threadIdx.x, ty = threadIdx.y; // (32, 8)
  #pragma unroll
  for (int r=0;r<4;r++){
    int f = f0 + ty + r*8;
    tile[ty+r*8][tx] = feat[(size_t)f*HWPX + j0 + tx];
  }
  __syncthreads();
  #pragma unroll
  for (int r=0;r<4;r++){
    int j = j0 + ty + r*8;
    featT[(size_t)j*FEAT + f0 + tx] = tile[tx][ty+r*8];
  }
}

// ---------------- build compacted per-class index lists + counts ----------------
__global__ __launch_bounds__(256) void k_index(const int* __restrict__ lab, float* ws){
  __shared__ int sc[256];
  int* idx = (int*)(ws + OFF_IDX);
  int* cnt = (int*)(ws + OFF_CNT);
  int t = threadIdx.x;
  int base = t*64;
  for (int c=1;c<=NCLS;c++){
    __syncthreads();
    int m = 0;
    for (int k=0;k<64;k++) m += (lab[base+k]==c) ? 1 : 0;
    sc[t] = m;
    __syncthreads();
    for (int off=1; off<256; off<<=1){
      int v = (t>=off)? sc[t-off] : 0;
      __syncthreads();
      sc[t] += v;
      __syncthreads();
    }
    int pos = sc[t] - m;
    if (t==255) cnt[c-1] = sc[255];
    int* ic = idx + (size_t)(c-1)*HWPX;
    for (int k=0;k<64;k++){
      if (lab[base+k]==c) ic[pos++] = base+k;
    }
  }
}

// ---------------- per-class feature-sum partials (deterministic, no atomics) ----------------
__global__ __launch_bounds__(256) void k_miu_part(const int* __restrict__ lab, float* ws){
  const float* featT = ws + OFF_FEATT;
  float* part = ws + OFF_MIUP;
  int f = threadIdx.x;
  int b = blockIdx.x;
  int j0 = b*512;
  float a0=0.f,a1=0.f,a2=0.f,a3=0.f;
  for (int j=j0;j<j0+512;j++){
    float v = featT[(size_t)j*FEAT + f];
    int c = lab[j];
    a0 += (c==1)? v : 0.f;
    a1 += (c==2)? v : 0.f;
    a2 += (c==3)? v : 0.f;
    a3 += (c==4)? v : 0.f;
  }
  float* pb = part + (size_t)b*NCLS*FEAT;
  pb[0*FEAT+f] = a0;
  pb[1*FEAT+f] = a1;
  pb[2*FEAT+f] = a2;
  pb[3*FEAT+f] = a3;
}

__global__ __launch_bounds__(1024) void k_miu_fin(float* ws){
  int t = threadIdx.x;            // 0..1023 = c*FEAT+f
  int c = t / FEAT;
  const float* part = ws + OFF_MIUP;
  float s = 0.f;
  for (int b=0;b<32;b++) s += part[(size_t)b*NCLS*FEAT + t];   // fixed order
  int n = ((int*)(ws+OFF_CNT))[c];
  float nf = fmaxf((float)n, 1.f);
  ws[OFF_MIU + t] = s / nf;
}

// ---------------- cov per class (64x64 tiles): G = m2mat/n - miu miu^T + eps I ----------------
__global__ __launch_bounds__(256) void k_cov(float* ws){
  __shared__ float Xa[32][68];
  __shared__ float Xb[32][68];
  const float* featT = ws + OFF_FEATT;
  int c = blockIdx.y;
  const int* idx = (const int*)(ws + OFF_IDX) + (size_t)c*HWPX;
  int n = ((int*)(ws+OFF_CNT))[c];
  float nf = fmaxf((float)n,1.f);
  const float* miu = ws + OFF_MIU + (size_t)c*FEAT;
  float* G = ws + OFF_G + (size_t)c*FEAT*FEAT;
  int fb = (blockIdx.x & 3)*64, gb = (blockIdx.x >> 2)*64;
  int t = threadIdx.x;
  int ti = t & 15, tj = t >> 4;
  float acc[4][4] = {};
  int jr = t >> 3;         // 0..31
  int s8 = (t & 7) * 8;    // 0..56
  int nch = (n + 31)/32;
  for (int ch=0; ch<nch; ch++){
    int jg = ch*32 + jr;
    __syncthreads();
    if (jg < n){
      int jx = idx[jg];
      const float* row = featT + (size_t)jx*FEAT;
      #pragma unroll
      for (int k=0;k<8;k++){ Xa[jr][s8+k] = row[fb+s8+k]; Xb[jr][s8+k] = row[gb+s8+k]; }
    } else {
      #pragma unroll
      for (int k=0;k<8;k++){ Xa[jr][s8+k] = 0.f; Xb[jr][s8+k] = 0.f; }
    }
    __syncthreads();
    for (int jj=0;jj<32;jj++){
      float4 av = *(const float4*)&Xa[jj][ti*4];
      float4 bv = *(const float4*)&Xb[jj][tj*4];
      float aa[4] = {av.x,av.y,av.z,av.w};
      float bb[4] = {bv.x,bv.y,bv.z,bv.w};
      #pragma unroll
      for (int ii=0; ii<4; ii++)
        #pragma unroll
        for (int j2=0; j2<4; j2++)
          acc[ii][j2] += aa[ii]*bb[j2];
    }
  }
  float eps = fminf(fmaxf(1e-5f/nf, 1e-8f), 1e-5f);
  #pragma unroll
  for (int ii=0; ii<4; ii++){
    #pragma unroll
    for (int j2=0; j2<4; j2++){
      int f = fb + ti*4 + ii, g = gb + tj*4 + j2;
      float v = acc[ii][j2]/nf - miu[f]*miu[g] + ((f==g)? eps : 0.f);
      G[(size_t)g*FEAT + f] = v;   // column-major, col g
    }
  }
}

// ---------------- register-resident one-sided cyclic Jacobi (per class block) ----------------
// 128 pairs x 8 lanes; each lane holds 32 elems of column P and 32 of column Q.
// Tournament movement: P-stream shifts pair->pair-1, Q-stream pair->pair+1
// (in-wave: shfl by 8 lanes; cross-wave: parity double-buffered LDS columns).
__global__ __launch_bounds__(1024) void k_jacobi(float* ws){
  __shared__ float colsq[256];
  __shared__ int srt[256];
  __shared__ int inv[256];
  __shared__ int sflag[NSWEEP];
  __shared__ float bP[2][16][256];
  __shared__ float bQ[2][16][256];
  __shared__ float bPn[2][16];
  __shared__ float bQn[2][16];
  int c = blockIdx.x;
  float* G = ws + OFF_G + (size_t)c*FEAT*FEAT;
  int t = threadIdx.x;
  int lane = t & 63;
  int wave = t >> 6;          // 0..15
  int pid  = t >> 3;          // 0..127
  int pw   = lane >> 3;       // pair-in-wave 0..7
  int ln   = t & 7;           // lane-in-pair 0..7

  if (t < NSWEEP) sflag[t] = 0;

  // initial columns at R=0: pid0 holds (255, 0); pid j holds (j, 255-j)
  float P[32], Q[32];
  {
    int p0 = (pid==0)? 255 : pid;
    int q0 = (pid==0)? 0   : 255 - pid;
    const float* cp = G + (size_t)p0*FEAT + ln*32;
    const float* cq = G + (size_t)q0*FEAT + ln*32;
    #pragma unroll
    for (int k=0;k<32;k+=4){
      float4 vp = *(const float4*)&cp[k];
      float4 vq = *(const float4*)&cq[k];
      P[k]=vp.x; P[k+1]=vp.y; P[k+2]=vp.z; P[k+3]=vp.w;
      Q[k]=vq.x; Q[k+1]=vq.y; Q[k+2]=vq.z; Q[k+3]=vq.w;
    }
  }
  __syncthreads();   // sflag init visible before any rotation sets it

  float pnorm, qnorm;
  int R = 0;
  for (int sw=0; sw<NSWEEP; sw++){
    // refresh norms from registers (fp32 drift reset once per sweep)
    {
      float sp=0.f, sq=0.f;
      #pragma unroll
      for (int k=0;k<32;k++){ sp += P[k]*P[k]; sq += Q[k]*Q[k]; }
      sp += __shfl_xor(sp,1); sp += __shfl_xor(sp,2); sp += __shfl_xor(sp,4);
      sq += __shfl_xor(sq,1); sq += __shfl_xor(sq,2); sq += __shfl_xor(sq,4);
      pnorm = sp; qnorm = sq;
    }
    for (int r=0; r<255; r++, R++){
      // ---- dot product (fixed order: per-lane 32 then xor-tree over 8 lanes) ----
      float d = 0.f;
      #pragma unroll
      for (int k=0;k<32;k++) d += P[k]*Q[k];
      d += __shfl_xor(d,1); d += __shfl_xor(d,2); d += __shfl_xor(d,4);
      float app = pnorm, aqq = qnorm;
      bool rot = (d*d > app*aqq*JTOL);
      if (rot){
        float tau = (aqq - app) / (2.f*d);
        float tt = copysignf(1.f, tau) / (fabsf(tau) + sqrtf(1.f + tau*tau));
        float cc = 1.f / sqrtf(1.f + tt*tt);
        float ssn = tt*cc;
        #pragma unroll
        for (int k=0;k<32;k++){
          float pk = P[k];
          P[k] = cc*pk - ssn*Q[k];
          Q[k] = ssn*pk + cc*Q[k];
        }
        pnorm = cc*cc*app - 2.f*cc*ssn*d + ssn*ssn*aqq;
        qnorm = ssn*ssn*app + 2.f*cc*ssn*d + cc*cc*aqq;
        if (ln == 0) sflag[sw] = 1;
      }
      // ---- boundary column writes (parity buffer) ----
      int par = R & 1;
      if (pw==0 && wave>0){
        float* row = &bP[par][wave][ln*32];
        #pragma unroll
        for (int k=0;k<32;k+=4){
          float4 v; v.x=P[k]; v.y=P[k+1]; v.z=P[k+2]; v.w=P[k+3];
          *(float4*)&row[k] = v;
        }
        if (ln==0) bPn[par][wave] = pnorm;
      }
      if (pw==7 && wave<15){
        float* row = &bQ[par][wave][ln*32];
        #pragma unroll
        for (int k=0;k<32;k+=4){
          float4 v; v.x=Q[k]; v.y=Q[k+1]; v.z=Q[k+2]; v.w=Q[k+3];
          *(float4*)&row[k] = v;
        }
        if (ln==0) bQn[par][wave] = qnorm;
      }
      __syncthreads();
      // ---- movement: newP_j = oldP_{j+1} (127: own oldQ); newQ_j = oldQ_{j-1} (1: oldQ_0; 0: oldP_1) ----
      bool rdP = (pw==7 && wave<15);
      bool rdQ = (pw==0 && wave>0);
      #pragma unroll
      for (int k0=0;k0<32;k0+=4){
        float4 bpn, bqp;
        if (rdP) bpn = *(const float4*)&bP[par][wave+1][ln*32+k0];
        if (rdQ) bqp = *(const float4*)&bQ[par][wave-1][ln*32+k0];
        #pragma unroll
        for (int j=0;j<4;j++){
          int k = k0+j;
          float pk = P[k], qk = Q[k];
          float ps = __shfl(pk, (lane+8)&63);
          float qs = __shfl(qk, (lane-8)&63);
          float np, nq;
          if (pid==0){ np = pk; nq = ps; }
          else       { np = ps; nq = qs; }
          if (pw==7) np = (wave==15)? qk : f4c(bpn,j);
          if (rdQ)   nq = f4c(bqp,j);
          P[k]=np; Q[k]=nq;
        }
      }
      {
        float pn2 = __shfl(pnorm,(lane+8)&63);
        float qn2 = __shfl(qnorm,(lane-8)&63);
        float npn, nqn;
        if (pid==0){ npn = pnorm; nqn = pn2; }
        else       { npn = pn2;  nqn = qn2; }
        if (pw==7) npn = (wave==15)? qnorm : bPn[par][wave+1];
        if (rdQ)   nqn = bQn[par][wave-1];
        pnorm = npn; qnorm = nqn;
      }
    }
    // ---- convergence check (deterministic: zero-rotation sweep => done) ----
    if (sflag[sw] == 0) break;
  }

  // ---- tail: final ids (R%255==0 => p=pid layout, or mid-sweep ids) ----
  int p, q;
  if (pid==0){ p = 255; q = R % 255; }
  else { p = (R + pid) % 255; q = (R + 255 - pid) % 255; }
  // exact final norms
  float sp=0.f, sq=0.f;
  #pragma unroll
  for (int k=0;k<32;k++){ sp += P[k]*P[k]; sq += Q[k]*Q[k]; }
  sp += __shfl_xor(sp,1); sp += __shfl_xor(sp,2); sp += __shfl_xor(sp,4);
  sq += __shfl_xor(sq,1); sq += __shfl_xor(sq,2); sq += __shfl_xor(sq,4);
  if (ln == 0){ colsq[p] = sp; colsq[q] = sq; }
  __syncthreads();
  // rank sort descending by norm^2 (ties by index)
  if (t < 256){
    float my = colsq[t];
    int rk = 0;
    for (int u=0; u<256; u++){
      float cu = colsq[u];
      rk += ((cu > my) || (cu == my && u < t)) ? 1 : 0;
    }
    srt[rk] = t;
  }
  __syncthreads();
  float* evals = ws + OFF_EVAL + (size_t)c*FEAT;
  if (t < 256){
    evals[t] = sqrtf(colsq[srt[t]]);
    inv[srt[t]] = t;
  }
  __syncthreads();
  // normalized eigenvector rows (sorted) straight from registers
  float* Et = ws + OFF_ETS + (size_t)c*FEAT*FEAT;
  int rkp = inv[p], rkq = inv[q];
  float ivp = 1.f / sqrtf(sp);
  float ivq = 1.f / sqrtf(sq);
  float* rp = Et + (size_t)rkp*FEAT + ln*32;
  float* rq = Et + (size_t)rkq*FEAT + ln*32;
  #pragma unroll
  for (int k=0;k<32;k+=4){
    float4 v; v.x=P[k]*ivp; v.y=P[k+1]*ivp; v.z=P[k+2]*ivp; v.w=P[k+3]*ivp;
    *(float4*)&rp[k] = v;
    float4 w2; w2.x=Q[k]*ivq; w2.y=Q[k+1]*ivq; w2.z=Q[k+2]*ivq; w2.w=Q[k+3]*ivq;
    *(float4*)&rq[k] = w2;
  }
}

// ---------------- B[c] = EtS (256x256, sorted) @ centered_gathered (256 x n_c) ----------------
__global__ __launch_bounds__(256) void k_bmat(float* ws){
  __shared__ float Ae[256][68];   // [f][k-local]
  __shared__ float Bc[256][68];   // [f][j-local]
  int c = blockIdx.z;
  int n = ((int*)(ws+OFF_CNT))[c];
  int j0 = blockIdx.x*64;
  if (j0 >= n) return;            // block-uniform
  int kb = blockIdx.y*64;
  const float* featT = ws + OFF_FEATT;
  const int* idx = (const int*)(ws + OFF_IDX) + (size_t)c*HWPX;
  const float* miu = ws + OFF_MIU + (size_t)c*FEAT;
  const float* Ets = ws + OFF_ETS + (size_t)c*FEAT*FEAT;
  float* Bg = ws + OFF_B + (size_t)c*FEAT*BCAP;
  int t = threadIdx.x;
  int l4 = t >> 2, sgf = (t & 3)*64;
  // stage Ae
  {
    const float* Erow = Ets + (size_t)(kb+l4)*FEAT + sgf;
    for (int f=0; f<64; f+=4){
      float4 v = *(const float4*)&Erow[f];
      Ae[sgf+f+0][l4] = v.x; Ae[sgf+f+1][l4] = v.y;
      Ae[sgf+f+2][l4] = v.z; Ae[sgf+f+3][l4] = v.w;
    }
  }
  // stage Bc (centered gathered columns)
  {
    int jg = j0 + l4;
    if (jg < n){
      const float* Frow = featT + (size_t)idx[jg]*FEAT + sgf;
      const float* mp = miu + sgf;
      for (int f=0; f<64; f+=4){
        float4 v = *(const float4*)&Frow[f];
        Bc[sgf+f+0][l4] = v.x - mp[f+0];
        Bc[sgf+f+1][l4] = v.y - mp[f+1];
        Bc[sgf+f+2][l4] = v.z - mp[f+2];
        Bc[sgf+f+3][l4] = v.w - mp[f+3];
      }
    } else {
      for (int f=0; f<64; f++) Bc[sgf+f][l4] = 0.f;
    }
  }
  __syncthreads();
  int ti = t & 15, tj = t >> 4;   // ti: k-sub, tj: j-sub
  float acc[4][4] = {};
  for (int f=0; f<FEAT; f+=4){
    #pragma unroll
    for (int ff=0; ff<4; ff++){
      float4 av = *(const float4*)&Ae[f+ff][ti*4];
      float4 bv = *(const float4*)&Bc[f+ff][tj*4];
      float aa[4] = {av.x,av.y,av.z,av.w};
      float bb[4] = {bv.x,bv.y,bv.z,bv.w};
      #pragma unroll
      for (int kk=0;kk<4;kk++)
        #pragma unroll
        for (int jj=0;jj<4;jj++)
          acc[kk][jj] += aa[kk]*bb[jj];
    }
  }
  #pragma unroll
  for (int kk=0; kk<4; kk++){
    float4 o; o.x=acc[kk][0]; o.y=acc[kk][1]; o.z=acc[kk][2]; o.w=acc[kk][3];
    *(float4*)&Bg[(size_t)(kb + ti*4 + kk)*BCAP + j0 + tj*4] = o;
  }
}

// ---------------- fp GEMM (pm @ B) with fused m2/m4 + per-block loss partials ----------------
__global__ __launch_bounds__(256) void k_fp(const float* __restrict__ pm, float* ws){
  __shared__ float As[256][68];   // [k][i-local]  (pm tile, transposed)
  __shared__ float Bs[256][68];   // [k][j-local]
  __shared__ float ev[256];
  __shared__ float red[64][17];
  __shared__ float m2s[64];
  __shared__ float m4s[64];
  int c = blockIdx.y;
  int i0 = blockIdx.x*64;
  int n = ((int*)(ws+OFF_CNT))[c];
  float nf = fmaxf((float)n, 1.f);
  const float* evals = ws + OFF_EVAL + (size_t)c*FEAT;
  const float* Bg = ws + OFF_B + (size_t)c*FEAT*BCAP;
  int t = threadIdx.x;
  int l4 = t >> 2;
  // stage As
  {
    int sgf = (t & 3)*64;
    int gi = i0 + l4;
    if (gi < NDIR){
      const float* row = pm + (size_t)gi*FEAT + sgf;
      for (int f=0; f<64; f+=4){
        float4 v = *(const float4*)&row[f];
        As[sgf+f+0][l4] = v.x; As[sgf+f+1][l4] = v.y;
        As[sgf+f+2][l4] = v.z; As[sgf+f+3][l4] = v.w;
      }
    } else {
      for (int f=0; f<64; f++) As[sgf+f][l4] = 0.f;
    }
  }
  if (t < 256) ev[t] = evals[t];
  int ti = t & 15, tj = t >> 4;
  float s2[4] = {0.f,0.f,0.f,0.f};
  float s4[4] = {0.f,0.f,0.f,0.f};
  int nch = (n + 63)/64;
  int sgj = (t & 3)*16;
  for (int ch=0; ch<nch; ch++){
    int j0 = ch*64;
    __syncthreads();
    for (int g=0; g<4; g++){
      int r = l4 + 64*g;
      const float* Brow = Bg + (size_t)r*BCAP + j0 + sgj;
      #pragma unroll
      for (int e=0; e<16; e+=4){
        int j = j0 + sgj + e;
        float4 v;
        if (j + 3 < n) v = *(const float4*)&Brow[e];
        else {
          v.x = (j+0<n)? Brow[e+0] : 0.f;
          v.y = (j+1<n)? Brow[e+1] : 0.f;
          v.z = (j+2<n)? Brow[e+2] : 0.f;
          v.w = (j+3<n)? Brow[e+3] : 0.f;
        }
        *(float4*)&Bs[r][sgj+e] = v;
      }
    }
    __syncthreads();
    float acc[4][4] = {};
    for (int k=0; k<FEAT; k+=4){
      #pragma unroll
      for (int kk=0; kk<4; kk++){
        float4 av = *(const float4*)&As[k+kk][ti*4];
        float4 bv = *(const float4*)&Bs[k+kk][tj*4];
        float aa[4] = {av.x,av.y,av.z,av.w};
        float bb[4] = {bv.x,bv.y,bv.z,bv.w};
        #pragma unroll
        for (int ii=0;ii<4;ii++)
          #pragma unroll
          for (int jj=0;jj<4;jj++)
            acc[ii][jj] += aa[ii]*bb[jj];
      }
    }
    #pragma unroll
    for (int ii=0;ii<4;ii++){
      #pragma unroll
      for (int jj=0;jj<4;jj++){
        float v = acc[ii][jj];
        float v2 = v*v;
        s2[ii] += v2;
        s4[ii] += v2*v2;
      }
    }
  }
  __syncthreads();
  #pragma unroll
  for (int ii=0;ii<4;ii++) red[ti*4+ii][tj] = s2[ii];
  __syncthreads();
  if (t < 64){
    float s = 0.f;
    for (int u=0;u<16;u++) s += red[t][u];
    m2s[t] = s;
  }
  __syncthreads();
  #pragma unroll
  for (int ii=0;ii<4;ii++) red[ti*4+ii][tj] = s4[ii];
  __syncthreads();
  if (t < 64){
    float s = 0.f;
    for (int u=0;u<16;u++) s += red[t][u];
    m4s[t] = s;
  }
  __syncthreads();
  if (t < 64){
    float stds = 0.f;
    for (int k=0;k<FEAT;k++){
      float a = As[k][t];
      stds += a*a*ev[k];
    }
    int i = i0 + t;
    float l2 = 0.f, lk = 0.f;
    if (i < NDIR){
      float m2 = m2s[t]/(nf*stds);
      float m4 = m4s[t]/(nf*stds*stds);
      float d2 = m2 - 1.f;
      l2 = d2*d2;
      float dk = m4 - 3.f*m2*m2;
      lk = dk*dk;
    }
    #pragma unroll
    for (int o=1;o<64;o<<=1){
      l2 += __shfl_xor(l2, o);
      lk += __shfl_xor(lk, o);
    }
    if (t == 0){
      float* lp = ws + OFF_LPART + ((size_t)c*160 + blockIdx.x)*2;
      lp[0] = l2;
      lp[1] = lk;
    }
  }
}

// ---------------- final scalar (deterministic fixed-order reduction) ----------------
__global__ __launch_bounds__(64) void k_final(float* ws, float* out){
  int t = threadIdx.x;   // one wave
  const int* cnt = (const int*)(ws + OFF_CNT);
  const float* lp = ws + OFF_LPART;
  float tot = 0.f, an = 0.f;
  for (int c=0;c<NCLS;c++){
    float s2 = 0.f, sk = 0.f;
    for (int b=t; b<NBLK_FP; b+=64){
      s2 += lp[((size_t)c*160 + b)*2 + 0];
      sk += lp[((size_t)c*160 + b)*2 + 1];
    }
    #pragma unroll
    for (int o=1;o<64;o<<=1){
      s2 += __shfl_xor(s2, o);
      sk += __shfl_xor(sk, o);
    }
    if (cnt[c] > 0){
      tot += s2/(float)NDIR + sk/(float)NDIR;
      an += 1.f;
    }
  }
  if (t == 0) out[0] = tot / fmaxf(an, 1.f);
}

extern "C" void kernel_launch(void* const* d_in, const int* in_sizes, int n_in,
                              void* d_out, int out_size, void* d_ws, size_t ws_size,
                              hipStream_t stream) {
  const float* feat = (const float*)d_in[0];
  const int*   lab  = (const int*)d_in[1];
  const float* pm   = (const float*)d_in[2];
  float* out = (float*)d_out;
  float* ws  = (float*)d_ws;

  hipLaunchKernelGGL(k_transpose, dim3(HWPX/32, FEAT/32), dim3(32,8), 0, stream, feat, ws);
  hipLaunchKernelGGL(k_index,     dim3(1),            dim3(256),     0, stream, lab, ws);
  hipLaunchKernelGGL(k_miu_part,  dim3(32),           dim3(256),     0, stream, lab, ws);
  hipLaunchKernelGGL(k_miu_fin,   dim3(1),            dim3(1024),    0, stream, ws);
  hipLaunchKernelGGL(k_cov,       dim3(16, NCLS),     dim3(256),     0, stream, ws);
  hipLaunchKernelGGL(k_jacobi,    dim3(NCLS),         dim3(1024),    0, stream, ws);
  hipLaunchKernelGGL(k_bmat,      dim3(BCAP/64, 4, NCLS), dim3(256), 0, stream, ws);
  hipLaunchKernelGGL(k_fp,        dim3(NBLK_FP, NCLS), dim3(256),    0, stream, pm, ws);
  hipLaunchKernelGGL(k_final,     dim3(1),            dim3(64),      0, stream, ws, out);
}

// Round 5
// 32637.466 us; speedup vs baseline: 1.3577x; 1.3577x over previous
//
#include <hip/hip_runtime.h>
#include <cstdint>
#include <cstddef>

#define FEAT 256
#define HWPX 16384
#define NDIR 10000
#define NCLS 4          // classes 1..4
#define BCAP 4096       // per-class column capacity for B (n_c ~ 3277)
#define NSWO 7          // outer block-Jacobi sweeps (fixed, deterministic; 7*31 % 31 == 0)
#define JTOL 4e-12f     // skip rotation if d^2 <= na*nb*JTOL
#define NBLK_FP 157     // ceil(NDIR/64)

// ---- workspace layout (element offsets; 4B elements) ----
static const size_t OFF_FEATT = 0;                                // 16384*256 f32
static const size_t OFF_IDX   = OFF_FEATT + (size_t)HWPX*FEAT;    // 4*16384 int
static const size_t OFF_CNT   = OFF_IDX + (size_t)NCLS*HWPX;      // 4 int (+pad)
static const size_t OFF_MIU   = OFF_CNT + 64;                     // 4*256 f32
static const size_t OFF_MIUP  = OFF_MIU + (size_t)NCLS*FEAT;      // 32*4*256 f32 partials
static const size_t OFF_G     = OFF_MIUP + (size_t)32*NCLS*FEAT;  // 4*65536 f32
static const size_t OFF_ETS   = OFF_G + (size_t)NCLS*FEAT*FEAT;   // 4*65536 f32
static const size_t OFF_EVAL  = OFF_ETS + (size_t)NCLS*FEAT*FEAT; // 4*256 f32
static const size_t OFF_LPART = OFF_EVAL + (size_t)NCLS*FEAT;     // 4*160*2 f32 per-block partials
static const size_t OFF_B     = OFF_LPART + (size_t)NCLS*160*2;   // 4*256*BCAP f32
static const size_t OFF_XCH   = OFF_B + (size_t)NCLS*FEAT*BCAP;   // 4*2*32*2048 f32 transit
// total ~ 39 MB

__device__ __forceinline__ float rdfirst(float v){
  return __int_as_float(__builtin_amdgcn_readfirstlane(__float_as_int(v)));
}

// 64-lane sum, result uniform (broadcast from lane 0's fixed-order value).
// 4 DPP row-rotate adds (16-lane allreduce, VALU pipe) + 2 bpermute stages.
__device__ __forceinline__ float wsum64(float v){
  int x;
  x = __builtin_amdgcn_update_dpp(0, __float_as_int(v), 0x121, 0xF, 0xF, false); v += __int_as_float(x); // row_ror:1
  x = __builtin_amdgcn_update_dpp(0, __float_as_int(v), 0x122, 0xF, 0xF, false); v += __int_as_float(x); // row_ror:2
  x = __builtin_amdgcn_update_dpp(0, __float_as_int(v), 0x124, 0xF, 0xF, false); v += __int_as_float(x); // row_ror:4
  x = __builtin_amdgcn_update_dpp(0, __float_as_int(v), 0x128, 0xF, 0xF, false); v += __int_as_float(x); // row_ror:8
  v += __shfl_xor(v, 16);
  v += __shfl_xor(v, 32);
  return rdfirst(v);
}

// ---------------- transpose feat (256 x 16384) -> featT (16384 x 256) ----------------
__global__ __launch_bounds__(256) void k_transpose(const float* __restrict__ feat, float* __restrict__ ws){
  __shared__ float tile[32][33];
  float* featT = ws + OFF_FEATT;
  int j0 = blockIdx.x*32, f0 = blockIdx.y*32;
  int tx = threadIdx.x, ty = threadIdx.y; // (32, 8)
  #pragma unroll
  for (int r=0;r<4;r++){
    int f = f0 + ty + r*8;
    tile[ty+r*8][tx] = feat[(size_t)f*HWPX + j0 + tx];
  }
  __syncthreads();
  #pragma unroll
  for (int r=0;r<4;r++){
    int j = j0 + ty + r*8;
    featT[(size_t)j*FEAT + f0 + tx] = tile[tx][ty+r*8];
  }
}

// ---------------- build compacted per-class index lists + counts ----------------
__global__ __launch_bounds__(256) void k_index(const int* __restrict__ lab, float* ws){
  __shared__ int sc[256];
  int* idx = (int*)(ws + OFF_IDX);
  int* cnt = (int*)(ws + OFF_CNT);
  int t = threadIdx.x;
  int base = t*64;
  for (int c=1;c<=NCLS;c++){
    __syncthreads();
    int m = 0;
    for (int k=0;k<64;k++) m += (lab[base+k]==c) ? 1 : 0;
    sc[t] = m;
    __syncthreads();
    for (int off=1; off<256; off<<=1){
      int v = (t>=off)? sc[t-off] : 0;
      __syncthreads();
      sc[t] += v;
      __syncthreads();
    }
    int pos = sc[t] - m;
    if (t==255) cnt[c-1] = sc[255];
    int* ic = idx + (size_t)(c-1)*HWPX;
    for (int k=0;k<64;k++){
      if (lab[base+k]==c) ic[pos++] = base+k;
    }
  }
}

// ---------------- per-class feature-sum partials (deterministic, no atomics) ----------------
__global__ __launch_bounds__(256) void k_miu_part(const int* __restrict__ lab, float* ws){
  const float* featT = ws + OFF_FEATT;
  float* part = ws + OFF_MIUP;
  int f = threadIdx.x;
  int b = blockIdx.x;
  int j0 = b*512;
  float a0=0.f,a1=0.f,a2=0.f,a3=0.f;
  for (int j=j0;j<j0+512;j++){
    float v = featT[(size_t)j*FEAT + f];
    int c = lab[j];
    a0 += (c==1)? v : 0.f;
    a1 += (c==2)? v : 0.f;
    a2 += (c==3)? v : 0.f;
    a3 += (c==4)? v : 0.f;
  }
  float* pb = part + (size_t)b*NCLS*FEAT;
  pb[0*FEAT+f] = a0;
  pb[1*FEAT+f] = a1;
  pb[2*FEAT+f] = a2;
  pb[3*FEAT+f] = a3;
}

__global__ __launch_bounds__(1024) void k_miu_fin(float* ws){
  int t = threadIdx.x;            // 0..1023 = c*FEAT+f
  int c = t / FEAT;
  const float* part = ws + OFF_MIUP;
  float s = 0.f;
  for (int b=0;b<32;b++) s += part[(size_t)b*NCLS*FEAT + t];   // fixed order
  int n = ((int*)(ws+OFF_CNT))[c];
  float nf = fmaxf((float)n, 1.f);
  ws[OFF_MIU + t] = s / nf;
}

// ---------------- cov per class (64x64 tiles): G = m2mat/n - miu miu^T + eps I ----------------
__global__ __launch_bounds__(256) void k_cov(float* ws){
  __shared__ float Xa[32][68];
  __shared__ float Xb[32][68];
  const float* featT = ws + OFF_FEATT;
  int c = blockIdx.y;
  const int* idx = (const int*)(ws + OFF_IDX) + (size_t)c*HWPX;
  int n = ((int*)(ws+OFF_CNT))[c];
  float nf = fmaxf((float)n,1.f);
  const float* miu = ws + OFF_MIU + (size_t)c*FEAT;
  float* G = ws + OFF_G + (size_t)c*FEAT*FEAT;
  int fb = (blockIdx.x & 3)*64, gb = (blockIdx.x >> 2)*64;
  int t = threadIdx.x;
  int ti = t & 15, tj = t >> 4;
  float acc[4][4] = {};
  int jr = t >> 3;         // 0..31
  int s8 = (t & 7) * 8;    // 0..56
  int nch = (n + 31)/32;
  for (int ch=0; ch<nch; ch++){
    int jg = ch*32 + jr;
    __syncthreads();
    if (jg < n){
      int jx = idx[jg];
      const float* row = featT + (size_t)jx*FEAT;
      #pragma unroll
      for (int k=0;k<8;k++){ Xa[jr][s8+k] = row[fb+s8+k]; Xb[jr][s8+k] = row[gb+s8+k]; }
    } else {
      #pragma unroll
      for (int k=0;k<8;k++){ Xa[jr][s8+k] = 0.f; Xb[jr][s8+k] = 0.f; }
    }
    __syncthreads();
    for (int jj=0;jj<32;jj++){
      float4 av = *(const float4*)&Xa[jj][ti*4];
      float4 bv = *(const float4*)&Xb[jj][tj*4];
      float aa[4] = {av.x,av.y,av.z,av.w};
      float bb[4] = {bv.x,bv.y,bv.z,bv.w};
      #pragma unroll
      for (int ii=0; ii<4; ii++)
        #pragma unroll
        for (int j2=0; j2<4; j2++)
          acc[ii][j2] += aa[ii]*bb[j2];
    }
  }
  float eps = fminf(fmaxf(1e-5f/nf, 1e-8f), 1e-5f);
  #pragma unroll
  for (int ii=0; ii<4; ii++){
    #pragma unroll
    for (int j2=0; j2<4; j2++){
      int f = fb + ti*4 + ii, g = gb + tj*4 + j2;
      float v = acc[ii][j2]/nf - miu[f]*miu[g] + ((f==g)? eps : 0.f);
      G[(size_t)g*FEAT + f] = v;   // column-major, col g
    }
  }
}

// ---------------- one-sided BLOCK Jacobi, row-resident registers ----------------
// 32 groups of 8 columns. Wave w owns a group-pair (16 cols); lane l owns rows
// 4l..4l+3 of all 16 (float4 C[16], static indices only). Inner sweep: 15
// micro-rounds x 8 pairs, barrier-free (rotations in-lane; dot via wsum64 ->
// lane-uniform angles). Outer tournament: 31 rounds/sweep, groups transit via
// double-buffered global buffer, ONE barrier per outer round.
__global__ __launch_bounds__(1024, 4) void k_jacobi(float* ws){
  __shared__ float colsq[256];
  __shared__ int srt[256];
  __shared__ int inv_[256];
  int c = blockIdx.x;
  float* G = ws + OFF_G + (size_t)c*FEAT*FEAT;
  float* X = ws + OFF_XCH + (size_t)c*2*32*2048;
  int t = threadIdx.x;
  int lane = t & 63;
  int w = t >> 6;             // wave 0..15
  float4 C[16];
  float nrm[16];

  int pg = (w==0)? 31 : w;        // initial (and final: NSWO*31 % 31 == 0) group ids
  int qg = (w==0)? 0  : 31 - w;
  #pragma unroll
  for (int j=0;j<8;j++)
    C[j] = *(const float4*)&G[(size_t)(pg*8+j)*FEAT + lane*4];
  #pragma unroll
  for (int j=0;j<8;j++)
    C[8+j] = *(const float4*)&G[(size_t)(qg*8+j)*FEAT + lane*4];

  for (int R=0; R<NSWO*31; R++){
    // exact column norms (refreshed each outer round; uniform across lanes)
    #pragma unroll
    for (int j=0;j<16;j++){
      float4 x = C[j];
      nrm[j] = wsum64(x.x*x.x + x.y*x.y + x.z*x.z + x.w*x.w);
    }
    // inner sweep: all 120 pairs of the 16 resident columns
    #pragma unroll
    for (int m=0;m<15;m++){
      #pragma unroll
      for (int k=0;k<8;k++){
        const int a = (k==0)? 15 : (m+k)%15;
        const int b = (k==0)? (m%15) : (m+15-k)%15;
        float dp = C[a].x*C[b].x + C[a].y*C[b].y + C[a].z*C[b].z + C[a].w*C[b].w;
        float d = wsum64(dp);
        float na = nrm[a], nb = nrm[b];
        if (d*d > na*nb*JTOL){            // wave-uniform branch
          float tau = (nb - na)/(2.f*d);
          float tt = copysignf(1.f,tau)/(fabsf(tau)+sqrtf(1.f+tau*tau));
          float cc = 1.f/sqrtf(1.f+tt*tt);
          float sn = tt*cc;
          float4 x = C[a], y = C[b], nx, ny;
          nx.x = cc*x.x - sn*y.x;  ny.x = sn*x.x + cc*y.x;
          nx.y = cc*x.y - sn*y.y;  ny.y = sn*x.y + cc*y.y;
          nx.z = cc*x.z - sn*y.z;  ny.z = sn*x.z + cc*y.z;
          nx.w = cc*x.w - sn*y.w;  ny.w = sn*x.w + cc*y.w;
          C[a] = nx; C[b] = ny;
          nrm[a] = cc*cc*na - 2.f*cc*sn*d + sn*sn*nb;
          nrm[b] = sn*sn*na + 2.f*cc*sn*d + cc*cc*nb;
        }
      }
    }
    // group transit (double-buffered global; one barrier per round)
    int par = R & 1;
    float* XB = X + (size_t)par*32*2048;
    if (w >= 1){
      #pragma unroll
      for (int j=0;j<8;j++)
        *(float4*)&XB[(size_t)w*2048 + j*256 + lane*4] = C[j];
    }
    if (w <= 14){
      #pragma unroll
      for (int j=0;j<8;j++)
        *(float4*)&XB[(size_t)(16+w)*2048 + j*256 + lane*4] = C[8+j];
    }
    __syncthreads();
    if (w == 15){
      #pragma unroll
      for (int j=0;j<8;j++) C[j] = C[8+j];             // newP = own oldQ
      #pragma unroll
      for (int j=0;j<8;j++)
        C[8+j] = *(const float4*)&XB[(size_t)(16+14)*2048 + j*256 + lane*4];  // oldQ_14
    } else if (w == 0){
      #pragma unroll
      for (int j=0;j<8;j++)
        C[8+j] = *(const float4*)&XB[(size_t)1*2048 + j*256 + lane*4];        // oldP_1
    } else {
      #pragma unroll
      for (int j=0;j<8;j++)
        C[j] = *(const float4*)&XB[(size_t)(w+1)*2048 + j*256 + lane*4];      // oldP_{w+1}
      #pragma unroll
      for (int j=0;j<8;j++)
        C[8+j] = *(const float4*)&XB[(size_t)(16+w-1)*2048 + j*256 + lane*4]; // oldQ_{w-1}
    }
  }

  // ---- extraction: exact norms, global rank-sort, normalized rows out ----
  #pragma unroll
  for (int j=0;j<16;j++){
    float4 x = C[j];
    nrm[j] = wsum64(x.x*x.x + x.y*x.y + x.z*x.z + x.w*x.w);
  }
  #pragma unroll
  for (int j=0;j<16;j++){
    int cid = (j<8)? (pg*8+j) : (qg*8+(j-8));
    if (lane == j) colsq[cid] = nrm[j];
  }
  __syncthreads();
  if (t < 256){
    float my = colsq[t];
    int rk = 0;
    for (int u=0; u<256; u++){
      float cu = colsq[u];
      rk += ((cu > my) || (cu == my && u < t)) ? 1 : 0;
    }
    srt[rk] = t;
  }
  __syncthreads();
  float* evals = ws + OFF_EVAL + (size_t)c*FEAT;
  if (t < 256){
    evals[t] = sqrtf(colsq[srt[t]]);
    inv_[srt[t]] = t;
  }
  __syncthreads();
  float* Et = ws + OFF_ETS + (size_t)c*FEAT*FEAT;
  #pragma unroll
  for (int j=0;j<16;j++){
    int cid = (j<8)? (pg*8+j) : (qg*8+(j-8));
    int rk = inv_[cid];
    float iv = 1.f / sqrtf(nrm[j]);
    float4 v = C[j];
    v.x*=iv; v.y*=iv; v.z*=iv; v.w*=iv;
    *(float4*)&Et[(size_t)rk*FEAT + lane*4] = v;
  }
}

// ---------------- B[c] = EtS (256x256, sorted) @ centered_gathered (256 x n_c) ----------------
__global__ __launch_bounds__(256) void k_bmat(float* ws){
  __shared__ float Ae[256][68];   // [f][k-local]
  __shared__ float Bc[256][68];   // [f][j-local]
  int c = blockIdx.z;
  int n = ((int*)(ws+OFF_CNT))[c];
  int j0 = blockIdx.x*64;
  if (j0 >= n) return;            // block-uniform
  int kb = blockIdx.y*64;
  const float* featT = ws + OFF_FEATT;
  const int* idx = (const int*)(ws + OFF_IDX) + (size_t)c*HWPX;
  const float* miu = ws + OFF_MIU + (size_t)c*FEAT;
  const float* Ets = ws + OFF_ETS + (size_t)c*FEAT*FEAT;
  float* Bg = ws + OFF_B + (size_t)c*FEAT*BCAP;
  int t = threadIdx.x;
  int l4 = t >> 2, sgf = (t & 3)*64;
  // stage Ae
  {
    const float* Erow = Ets + (size_t)(kb+l4)*FEAT + sgf;
    for (int f=0; f<64; f+=4){
      float4 v = *(const float4*)&Erow[f];
      Ae[sgf+f+0][l4] = v.x; Ae[sgf+f+1][l4] = v.y;
      Ae[sgf+f+2][l4] = v.z; Ae[sgf+f+3][l4] = v.w;
    }
  }
  // stage Bc (centered gathered columns)
  {
    int jg = j0 + l4;
    if (jg < n){
      const float* Frow = featT + (size_t)idx[jg]*FEAT + sgf;
      const float* mp = miu + sgf;
      for (int f=0; f<64; f+=4){
        float4 v = *(const float4*)&Frow[f];
        Bc[sgf+f+0][l4] = v.x - mp[f+0];
        Bc[sgf+f+1][l4] = v.y - mp[f+1];
        Bc[sgf+f+2][l4] = v.z - mp[f+2];
        Bc[sgf+f+3][l4] = v.w - mp[f+3];
      }
    } else {
      for (int f=0; f<64; f++) Bc[sgf+f][l4] = 0.f;
    }
  }
  __syncthreads();
  int ti = t & 15, tj = t >> 4;   // ti: k-sub, tj: j-sub
  float acc[4][4] = {};
  for (int f=0; f<FEAT; f+=4){
    #pragma unroll
    for (int ff=0; ff<4; ff++){
      float4 av = *(const float4*)&Ae[f+ff][ti*4];
      float4 bv = *(const float4*)&Bc[f+ff][tj*4];
      float aa[4] = {av.x,av.y,av.z,av.w};
      float bb[4] = {bv.x,bv.y,bv.z,bv.w};
      #pragma unroll
      for (int kk=0;kk<4;kk++)
        #pragma unroll
        for (int jj=0;jj<4;jj++)
          acc[kk][jj] += aa[kk]*bb[jj];
    }
  }
  #pragma unroll
  for (int kk=0; kk<4; kk++){
    float4 o; o.x=acc[kk][0]; o.y=acc[kk][1]; o.z=acc[kk][2]; o.w=acc[kk][3];
    *(float4*)&Bg[(size_t)(kb + ti*4 + kk)*BCAP + j0 + tj*4] = o;
  }
}

// ---------------- fp GEMM (pm @ B) with fused m2/m4 + per-block loss partials ----------------
__global__ __launch_bounds__(256) void k_fp(const float* __restrict__ pm, float* ws){
  __shared__ float As[256][68];   // [k][i-local]  (pm tile, transposed)
  __shared__ float Bs[256][68];   // [k][j-local]
  __shared__ float ev[256];
  __shared__ float red[64][17];
  __shared__ float m2s[64];
  __shared__ float m4s[64];
  int c = blockIdx.y;
  int i0 = blockIdx.x*64;
  int n = ((int*)(ws+OFF_CNT))[c];
  float nf = fmaxf((float)n, 1.f);
  const float* evals = ws + OFF_EVAL + (size_t)c*FEAT;
  const float* Bg = ws + OFF_B + (size_t)c*FEAT*BCAP;
  int t = threadIdx.x;
  int l4 = t >> 2;
  // stage As
  {
    int sgf = (t & 3)*64;
    int gi = i0 + l4;
    if (gi < NDIR){
      const float* row = pm + (size_t)gi*FEAT + sgf;
      for (int f=0; f<64; f+=4){
        float4 v = *(const float4*)&row[f];
        As[sgf+f+0][l4] = v.x; As[sgf+f+1][l4] = v.y;
        As[sgf+f+2][l4] = v.z; As[sgf+f+3][l4] = v.w;
      }
    } else {
      for (int f=0; f<64; f++) As[sgf+f][l4] = 0.f;
    }
  }
  if (t < 256) ev[t] = evals[t];
  int ti = t & 15, tj = t >> 4;
  float s2[4] = {0.f,0.f,0.f,0.f};
  float s4[4] = {0.f,0.f,0.f,0.f};
  int nch = (n + 63)/64;
  int sgj = (t & 3)*16;
  for (int ch=0; ch<nch; ch++){
    int j0 = ch*64;
    __syncthreads();
    for (int g=0; g<4; g++){
      int r = l4 + 64*g;
      const float* Brow = Bg + (size_t)r*BCAP + j0 + sgj;
      #pragma unroll
      for (int e=0; e<16; e+=4){
        int j = j0 + sgj + e;
        float4 v;
        if (j + 3 < n) v = *(const float4*)&Brow[e];
        else {
          v.x = (j+0<n)? Brow[e+0] : 0.f;
          v.y = (j+1<n)? Brow[e+1] : 0.f;
          v.z = (j+2<n)? Brow[e+2] : 0.f;
          v.w = (j+3<n)? Brow[e+3] : 0.f;
        }
        *(float4*)&Bs[r][sgj+e] = v;
      }
    }
    __syncthreads();
    float acc[4][4] = {};
    for (int k=0; k<FEAT; k+=4){
      #pragma unroll
      for (int kk=0; kk<4; kk++){
        float4 av = *(const float4*)&As[k+kk][ti*4];
        float4 bv = *(const float4*)&Bs[k+kk][tj*4];
        float aa[4] = {av.x,av.y,av.z,av.w};
        float bb[4] = {bv.x,bv.y,bv.z,bv.w};
        #pragma unroll
        for (int ii=0;ii<4;ii++)
          #pragma unroll
          for (int jj=0;jj<4;jj++)
            acc[ii][jj] += aa[ii]*bb[jj];
      }
    }
    #pragma unroll
    for (int ii=0;ii<4;ii++){
      #pragma unroll
      for (int jj=0;jj<4;jj++){
        float v = acc[ii][jj];
        float v2 = v*v;
        s2[ii] += v2;
        s4[ii] += v2*v2;
      }
    }
  }
  __syncthreads();
  #pragma unroll
  for (int ii=0;ii<4;ii++) red[ti*4+ii][tj] = s2[ii];
  __syncthreads();
  if (t < 64){
    float s = 0.f;
    for (int u=0;u<16;u++) s += red[t][u];
    m2s[t] = s;
  }
  __syncthreads();
  #pragma unroll
  for (int ii=0;ii<4;ii++) red[ti*4+ii][tj] = s4[ii];
  __syncthreads();
  if (t < 64){
    float s = 0.f;
    for (int u=0;u<16;u++) s += red[t][u];
    m4s[t] = s;
  }
  __syncthreads();
  if (t < 64){
    float stds = 0.f;
    for (int k=0;k<FEAT;k++){
      float a = As[k][t];
      stds += a*a*ev[k];
    }
    int i = i0 + t;
    float l2 = 0.f, lk = 0.f;
    if (i < NDIR){
      float m2 = m2s[t]/(nf*stds);
      float m4 = m4s[t]/(nf*stds*stds);
      float d2 = m2 - 1.f;
      l2 = d2*d2;
      float dk = m4 - 3.f*m2*m2;
      lk = dk*dk;
    }
    #pragma unroll
    for (int o=1;o<64;o<<=1){
      l2 += __shfl_xor(l2, o);
      lk += __shfl_xor(lk, o);
    }
    if (t == 0){
      float* lp = ws + OFF_LPART + ((size_t)c*160 + blockIdx.x)*2;
      lp[0] = l2;
      lp[1] = lk;
    }
  }
}

// ---------------- final scalar (deterministic fixed-order reduction) ----------------
__global__ __launch_bounds__(64) void k_final(float* ws, float* out){
  int t = threadIdx.x;   // one wave
  const int* cnt = (const int*)(ws + OFF_CNT);
  const float* lp = ws + OFF_LPART;
  float tot = 0.f, an = 0.f;
  for (int c=0;c<NCLS;c++){
    float s2 = 0.f, sk = 0.f;
    for (int b=t; b<NBLK_FP; b+=64){
      s2 += lp[((size_t)c*160 + b)*2 + 0];
      sk += lp[((size_t)c*160 + b)*2 + 1];
    }
    #pragma unroll
    for (int o=1;o<64;o<<=1){
      s2 += __shfl_xor(s2, o);
      sk += __shfl_xor(sk, o);
    }
    if (cnt[c] > 0){
      tot += s2/(float)NDIR + sk/(float)NDIR;
      an += 1.f;
    }
  }
  if (t == 0) out[0] = tot / fmaxf(an, 1.f);
}

extern "C" void kernel_launch(void* const* d_in, const int* in_sizes, int n_in,
                              void* d_out, int out_size, void* d_ws, size_t ws_size,
                              hipStream_t stream) {
  const float* feat = (const float*)d_in[0];
  const int*   lab  = (const int*)d_in[1];
  const float* pm   = (const float*)d_in[2];
  float* out = (float*)d_out;
  float* ws  = (float*)d_ws;

  hipLaunchKernelGGL(k_transpose, dim3(HWPX/32, FEAT/32), dim3(32,8), 0, stream, feat, ws);
  hipLaunchKernelGGL(k_index,     dim3(1),            dim3(256),     0, stream, lab, ws);
  hipLaunchKernelGGL(k_miu_part,  dim3(32),           dim3(256),     0, stream, lab, ws);
  hipLaunchKernelGGL(k_miu_fin,   dim3(1),            dim3(1024),    0, stream, ws);
  hipLaunchKernelGGL(k_cov,       dim3(16, NCLS),     dim3(256),     0, stream, ws);
  hipLaunchKernelGGL(k_jacobi,    dim3(NCLS),         dim3(1024),    0, stream, ws);
  hipLaunchKernelGGL(k_bmat,      dim3(BCAP/64, 4, NCLS), dim3(256), 0, stream, ws);
  hipLaunchKernelGGL(k_fp,        dim3(NBLK_FP, NCLS), dim3(256),    0, stream, pm, ws);
  hipLaunchKernelGGL(k_final,     dim3(1),            dim3(64),      0, stream, ws, out);
}

// Round 6
// 24455.345 us; speedup vs baseline: 1.8120x; 1.3346x over previous
//
#include <hip/hip_runtime.h>
#include <cstdint>
#include <cstddef>

#define FEAT 256
#define HWPX 16384
#define NDIR 10000
#define NCLS 4          // classes 1..4
#define BCAP 4096       // per-class column capacity for B (n_c ~ 3277)
#define NSWO 7          // outer block-Jacobi sweeps (fixed, deterministic; 7*31 % 31 == 0)
#define JTOL 4e-12f     // skip rotation if d^2 <= na*nb*JTOL
#define NBLK_FP 157     // ceil(NDIR/64)

// ---- workspace layout (element offsets; 4B elements) ----
static const size_t OFF_FEATT = 0;                                // 16384*256 f32
static const size_t OFF_IDX   = OFF_FEATT + (size_t)HWPX*FEAT;    // 4*16384 int
static const size_t OFF_CNT   = OFF_IDX + (size_t)NCLS*HWPX;      // 4 int (+pad)
static const size_t OFF_MIU   = OFF_CNT + 64;                     // 4*256 f32
static const size_t OFF_MIUP  = OFF_MIU + (size_t)NCLS*FEAT;      // 32*4*256 f32 partials
static const size_t OFF_G     = OFF_MIUP + (size_t)32*NCLS*FEAT;  // 4*65536 f32
static const size_t OFF_ETS   = OFF_G + (size_t)NCLS*FEAT*FEAT;   // 4*65536 f32
static const size_t OFF_EVAL  = OFF_ETS + (size_t)NCLS*FEAT*FEAT; // 4*256 f32
static const size_t OFF_LPART = OFF_EVAL + (size_t)NCLS*FEAT;     // 4*160*2 f32 per-block partials
static const size_t OFF_B     = OFF_LPART + (size_t)NCLS*160*2;   // 4*256*BCAP f32
static const size_t OFF_XCH   = OFF_B + (size_t)NCLS*FEAT*BCAP;   // 4*2*32*2048 f32 transit
// total ~ 39 MB

__device__ __forceinline__ float rdfirst(float v){
  return __int_as_float(__builtin_amdgcn_readfirstlane(__float_as_int(v)));
}

// 64-lane sum, result uniform (broadcast from lane 0's fixed-order value).
__device__ __forceinline__ float wsum64(float v){
  int x;
  x = __builtin_amdgcn_update_dpp(0, __float_as_int(v), 0x121, 0xF, 0xF, false); v += __int_as_float(x); // row_ror:1
  x = __builtin_amdgcn_update_dpp(0, __float_as_int(v), 0x122, 0xF, 0xF, false); v += __int_as_float(x); // row_ror:2
  x = __builtin_amdgcn_update_dpp(0, __float_as_int(v), 0x124, 0xF, 0xF, false); v += __int_as_float(x); // row_ror:4
  x = __builtin_amdgcn_update_dpp(0, __float_as_int(v), 0x128, 0xF, 0xF, false); v += __int_as_float(x); // row_ror:8
  v += __shfl_xor(v, 16);
  v += __shfl_xor(v, 32);
  return rdfirst(v);
}

// ---------------- transpose feat (256 x 16384) -> featT (16384 x 256) ----------------
__global__ __launch_bounds__(256) void k_transpose(const float* __restrict__ feat, float* __restrict__ ws){
  __shared__ float tile[32][33];
  float* featT = ws + OFF_FEATT;
  int j0 = blockIdx.x*32, f0 = blockIdx.y*32;
  int tx = threadIdx.x, ty = threadIdx.y; // (32, 8)
  #pragma unroll
  for (int r=0;r<4;r++){
    int f = f0 + ty + r*8;
    tile[ty+r*8][tx] = feat[(size_t)f*HWPX + j0 + tx];
  }
  __syncthreads();
  #pragma unroll
  for (int r=0;r<4;r++){
    int j = j0 + ty + r*8;
    featT[(size_t)j*FEAT + f0 + tx] = tile[tx][ty+r*8];
  }
}

// ---------------- build compacted per-class index lists + counts ----------------
__global__ __launch_bounds__(256) void k_index(const int* __restrict__ lab, float* ws){
  __shared__ int sc[256];
  int* idx = (int*)(ws + OFF_IDX);
  int* cnt = (int*)(ws + OFF_CNT);
  int t = threadIdx.x;
  int base = t*64;
  for (int c=1;c<=NCLS;c++){
    __syncthreads();
    int m = 0;
    for (int k=0;k<64;k++) m += (lab[base+k]==c) ? 1 : 0;
    sc[t] = m;
    __syncthreads();
    for (int off=1; off<256; off<<=1){
      int v = (t>=off)? sc[t-off] : 0;
      __syncthreads();
      sc[t] += v;
      __syncthreads();
    }
    int pos = sc[t] - m;
    if (t==255) cnt[c-1] = sc[255];
    int* ic = idx + (size_t)(c-1)*HWPX;
    for (int k=0;k<64;k++){
      if (lab[base+k]==c) ic[pos++] = base+k;
    }
  }
}

// ---------------- per-class feature-sum partials (deterministic, no atomics) ----------------
__global__ __launch_bounds__(256) void k_miu_part(const int* __restrict__ lab, float* ws){
  const float* featT = ws + OFF_FEATT;
  float* part = ws + OFF_MIUP;
  int f = threadIdx.x;
  int b = blockIdx.x;
  int j0 = b*512;
  float a0=0.f,a1=0.f,a2=0.f,a3=0.f;
  for (int j=j0;j<j0+512;j++){
    float v = featT[(size_t)j*FEAT + f];
    int c = lab[j];
    a0 += (c==1)? v : 0.f;
    a1 += (c==2)? v : 0.f;
    a2 += (c==3)? v : 0.f;
    a3 += (c==4)? v : 0.f;
  }
  float* pb = part + (size_t)b*NCLS*FEAT;
  pb[0*FEAT+f] = a0;
  pb[1*FEAT+f] = a1;
  pb[2*FEAT+f] = a2;
  pb[3*FEAT+f] = a3;
}

__global__ __launch_bounds__(1024) void k_miu_fin(float* ws){
  int t = threadIdx.x;            // 0..1023 = c*FEAT+f
  int c = t / FEAT;
  const float* part = ws + OFF_MIUP;
  float s = 0.f;
  for (int b=0;b<32;b++) s += part[(size_t)b*NCLS*FEAT + t];   // fixed order
  int n = ((int*)(ws+OFF_CNT))[c];
  float nf = fmaxf((float)n, 1.f);
  ws[OFF_MIU + t] = s / nf;
}

// ---------------- cov per class (64x64 tiles): G = m2mat/n - miu miu^T + eps I ----------------
__global__ __launch_bounds__(256) void k_cov(float* ws){
  __shared__ float Xa[32][68];
  __shared__ float Xb[32][68];
  const float* featT = ws + OFF_FEATT;
  int c = blockIdx.y;
  const int* idx = (const int*)(ws + OFF_IDX) + (size_t)c*HWPX;
  int n = ((int*)(ws+OFF_CNT))[c];
  float nf = fmaxf((float)n,1.f);
  const float* miu = ws + OFF_MIU + (size_t)c*FEAT;
  float* G = ws + OFF_G + (size_t)c*FEAT*FEAT;
  int fb = (blockIdx.x & 3)*64, gb = (blockIdx.x >> 2)*64;
  int t = threadIdx.x;
  int ti = t & 15, tj = t >> 4;
  float acc[4][4] = {};
  int jr = t >> 3;         // 0..31
  int s8 = (t & 7) * 8;    // 0..56
  int nch = (n + 31)/32;
  for (int ch=0; ch<nch; ch++){
    int jg = ch*32 + jr;
    __syncthreads();
    if (jg < n){
      int jx = idx[jg];
      const float* row = featT + (size_t)jx*FEAT;
      #pragma unroll
      for (int k=0;k<8;k++){ Xa[jr][s8+k] = row[fb+s8+k]; Xb[jr][s8+k] = row[gb+s8+k]; }
    } else {
      #pragma unroll
      for (int k=0;k<8;k++){ Xa[jr][s8+k] = 0.f; Xb[jr][s8+k] = 0.f; }
    }
    __syncthreads();
    for (int jj=0;jj<32;jj++){
      float4 av = *(const float4*)&Xa[jj][ti*4];
      float4 bv = *(const float4*)&Xb[jj][tj*4];
      float aa[4] = {av.x,av.y,av.z,av.w};
      float bb[4] = {bv.x,bv.y,bv.z,bv.w};
      #pragma unroll
      for (int ii=0; ii<4; ii++)
        #pragma unroll
        for (int j2=0; j2<4; j2++)
          acc[ii][j2] += aa[ii]*bb[j2];
    }
  }
  float eps = fminf(fmaxf(1e-5f/nf, 1e-8f), 1e-5f);
  #pragma unroll
  for (int ii=0; ii<4; ii++){
    #pragma unroll
    for (int j2=0; j2<4; j2++){
      int f = fb + ti*4 + ii, g = gb + tj*4 + j2;
      float v = acc[ii][j2]/nf - miu[f]*miu[g] + ((f==g)? eps : 0.f);
      G[(size_t)g*FEAT + f] = v;   // column-major, col g
    }
  }
}

// ---------------- one-sided BLOCK Jacobi, STATIC named registers ----------------
// 32 groups of 8 columns. Wave w owns a group-pair (16 cols = C0..C15); lane l
// owns rows 4l..4l+3. 120-pair inner sweep fully expanded with literal indices
// (no dynamic register indexing -> no cndmask emulation / spill). One barrier
// per outer round; transit via double-buffered global buffer.
__global__ __launch_bounds__(1024, 4) void k_jacobi(float* ws){
  __shared__ float colsq[256];
  __shared__ int srt[256];
  __shared__ int inv_[256];
  int c = blockIdx.x;
  float* G = ws + OFF_G + (size_t)c*FEAT*FEAT;
  float* X = ws + OFF_XCH + (size_t)c*2*32*2048;
  int t = threadIdx.x;
  int lane = t & 63;
  int w = t >> 6;             // wave 0..15

  float4 C0,C1,C2,C3,C4,C5,C6,C7,C8,C9,C10,C11,C12,C13,C14,C15;
  float n0,n1,n2,n3,n4,n5,n6,n7,n8,n9,n10,n11,n12,n13,n14,n15;

  int pg = (w==0)? 31 : w;        // initial (and final: NSWO*31 % 31 == 0) group ids
  int qg = (w==0)? 0  : 31 - w;

#define FORJ16(M) M(0) M(1) M(2) M(3) M(4) M(5) M(6) M(7) M(8) M(9) M(10) M(11) M(12) M(13) M(14) M(15)
#define FORJ8L(M) M(0) M(1) M(2) M(3) M(4) M(5) M(6) M(7)
#define FORJ8H(M) M(8) M(9) M(10) M(11) M(12) M(13) M(14) M(15)

#define LDC(j) C##j = *(const float4*)&G[(size_t)(((j)<8)? (pg*8+(j)) : (qg*8+(j)-8))*FEAT + lane*4];
  FORJ16(LDC)
#undef LDC

#define NRMJ(j) { float4 x = C##j; n##j = wsum64(x.x*x.x + x.y*x.y + x.z*x.z + x.w*x.w); }

#define ROT(ia, ib) { \
    float dp = C##ia.x*C##ib.x + C##ia.y*C##ib.y + C##ia.z*C##ib.z + C##ia.w*C##ib.w; \
    float d = wsum64(dp); \
    float na = n##ia, nb = n##ib; \
    if (d*d > na*nb*JTOL){ \
      float tau = (nb - na)/(2.f*d); \
      float tt = copysignf(1.f,tau)/(fabsf(tau)+sqrtf(1.f+tau*tau)); \
      float cc = 1.f/sqrtf(1.f+tt*tt); \
      float sn = tt*cc; \
      float4 x = C##ia, y = C##ib; \
      C##ia.x = cc*x.x - sn*y.x;  C##ib.x = sn*x.x + cc*y.x; \
      C##ia.y = cc*x.y - sn*y.y;  C##ib.y = sn*x.y + cc*y.y; \
      C##ia.z = cc*x.z - sn*y.z;  C##ib.z = sn*x.z + cc*y.z; \
      C##ia.w = cc*x.w - sn*y.w;  C##ib.w = sn*x.w + cc*y.w; \
      n##ia = cc*cc*na - 2.f*cc*sn*d + sn*sn*nb; \
      n##ib = sn*sn*na + 2.f*cc*sn*d + cc*cc*nb; \
    } \
  }

  for (int R=0; R<NSWO*31; R++){
    // exact column norms (refreshed each outer round; uniform across lanes)
    FORJ16(NRMJ)
    // inner sweep: all 120 pairs, round-robin tournament (m=0..14, k=0..7)
    ROT(15,0)  ROT(1,14)  ROT(2,13)  ROT(3,12)  ROT(4,11)  ROT(5,10)  ROT(6,9)   ROT(7,8)
    ROT(15,1)  ROT(2,0)   ROT(3,14)  ROT(4,13)  ROT(5,12)  ROT(6,11)  ROT(7,10)  ROT(8,9)
    ROT(15,2)  ROT(3,1)   ROT(4,0)   ROT(5,14)  ROT(6,13)  ROT(7,12)  ROT(8,11)  ROT(9,10)
    ROT(15,3)  ROT(4,2)   ROT(5,1)   ROT(6,0)   ROT(7,14)  ROT(8,13)  ROT(9,12)  ROT(10,11)
    ROT(15,4)  ROT(5,3)   ROT(6,2)   ROT(7,1)   ROT(8,0)   ROT(9,14)  ROT(10,13) ROT(11,12)
    ROT(15,5)  ROT(6,4)   ROT(7,3)   ROT(8,2)   ROT(9,1)   ROT(10,0)  ROT(11,14) ROT(12,13)
    ROT(15,6)  ROT(7,5)   ROT(8,4)   ROT(9,3)   ROT(10,2)  ROT(11,1)  ROT(12,0)  ROT(13,14)
    ROT(15,7)  ROT(8,6)   ROT(9,5)   ROT(10,4)  ROT(11,3)  ROT(12,2)  ROT(13,1)  ROT(14,0)
    ROT(15,8)  ROT(9,7)   ROT(10,6)  ROT(11,5)  ROT(12,4)  ROT(13,3)  ROT(14,2)  ROT(0,1)
    ROT(15,9)  ROT(10,8)  ROT(11,7)  ROT(12,6)  ROT(13,5)  ROT(14,4)  ROT(0,3)   ROT(1,2)
    ROT(15,10) ROT(11,9)  ROT(12,8)  ROT(13,7)  ROT(14,6)  ROT(0,5)   ROT(1,4)   ROT(2,3)
    ROT(15,11) ROT(12,10) ROT(13,9)  ROT(14,8)  ROT(0,7)   ROT(1,6)   ROT(2,5)   ROT(3,4)
    ROT(15,12) ROT(13,11) ROT(14,10) ROT(0,9)   ROT(1,8)   ROT(2,7)   ROT(3,6)   ROT(4,5)
    ROT(15,13) ROT(14,12) ROT(0,11)  ROT(1,10)  ROT(2,9)   ROT(3,8)   ROT(4,7)   ROT(5,6)
    ROT(15,14) ROT(0,13)  ROT(1,12)  ROT(2,11)  ROT(3,10)  ROT(4,9)   ROT(5,8)   ROT(6,7)

    // group transit (double-buffered global; one barrier per round)
    int par = R & 1;
    float* XB = X + (size_t)par*32*2048;
    if (w >= 1){
#define STP(j) *(float4*)&XB[(size_t)w*2048 + (j)*256 + lane*4] = C##j;
      FORJ8L(STP)
#undef STP
    }
    if (w <= 14){
#define STQ(j) *(float4*)&XB[(size_t)(16+w)*2048 + ((j)-8)*256 + lane*4] = C##j;
      FORJ8H(STQ)
#undef STQ
    }
    __syncthreads();
    if (w == 15){
      C0=C8; C1=C9; C2=C10; C3=C11; C4=C12; C5=C13; C6=C14; C7=C15;   // newP = own oldQ
#define LQ(j) C##j = *(const float4*)&XB[(size_t)(16+14)*2048 + ((j)-8)*256 + lane*4];
      FORJ8H(LQ)                                                       // oldQ_14
#undef LQ
    } else if (w == 0){
#define LQ(j) C##j = *(const float4*)&XB[(size_t)1*2048 + ((j)-8)*256 + lane*4];
      FORJ8H(LQ)                                                       // oldP_1
#undef LQ
    } else {
#define LP(j) C##j = *(const float4*)&XB[(size_t)(w+1)*2048 + (j)*256 + lane*4];
      FORJ8L(LP)                                                       // oldP_{w+1}
#undef LP
#define LQ(j) C##j = *(const float4*)&XB[(size_t)(16+w-1)*2048 + ((j)-8)*256 + lane*4];
      FORJ8H(LQ)                                                       // oldQ_{w-1}
#undef LQ
    }
  }

  // ---- extraction: exact norms, global rank-sort, normalized rows out ----
  FORJ16(NRMJ)
#define WCS(j) if (lane == (j)) colsq[((j)<8)? (pg*8+(j)) : (qg*8+(j)-8)] = n##j;
  FORJ16(WCS)
#undef WCS
  __syncthreads();
  if (t < 256){
    float my = colsq[t];
    int rk = 0;
    for (int u=0; u<256; u++){
      float cu = colsq[u];
      rk += ((cu > my) || (cu == my && u < t)) ? 1 : 0;
    }
    srt[rk] = t;
  }
  __syncthreads();
  float* evals = ws + OFF_EVAL + (size_t)c*FEAT;
  if (t < 256){
    evals[t] = sqrtf(colsq[srt[t]]);
    inv_[srt[t]] = t;
  }
  __syncthreads();
  float* Et = ws + OFF_ETS + (size_t)c*FEAT*FEAT;
#define WET(j) { \
    int cid = ((j)<8)? (pg*8+(j)) : (qg*8+(j)-8); \
    int rk = inv_[cid]; \
    float iv = 1.f / sqrtf(n##j); \
    float4 v = C##j; \
    v.x*=iv; v.y*=iv; v.z*=iv; v.w*=iv; \
    *(float4*)&Et[(size_t)rk*FEAT + lane*4] = v; \
  }
  FORJ16(WET)
#undef WET
#undef ROT
#undef NRMJ
#undef FORJ16
#undef FORJ8L
#undef FORJ8H
}

// ---------------- B[c] = EtS (256x256, sorted) @ centered_gathered (256 x n_c) ----------------
__global__ __launch_bounds__(256) void k_bmat(float* ws){
  __shared__ float Ae[256][68];   // [f][k-local]
  __shared__ float Bc[256][68];   // [f][j-local]
  int c = blockIdx.z;
  int n = ((int*)(ws+OFF_CNT))[c];
  int j0 = blockIdx.x*64;
  if (j0 >= n) return;            // block-uniform
  int kb = blockIdx.y*64;
  const float* featT = ws + OFF_FEATT;
  const int* idx = (const int*)(ws + OFF_IDX) + (size_t)c*HWPX;
  const float* miu = ws + OFF_MIU + (size_t)c*FEAT;
  const float* Ets = ws + OFF_ETS + (size_t)c*FEAT*FEAT;
  float* Bg = ws + OFF_B + (size_t)c*FEAT*BCAP;
  int t = threadIdx.x;
  int l4 = t >> 2, sgf = (t & 3)*64;
  // stage Ae
  {
    const float* Erow = Ets + (size_t)(kb+l4)*FEAT + sgf;
    for (int f=0; f<64; f+=4){
      float4 v = *(const float4*)&Erow[f];
      Ae[sgf+f+0][l4] = v.x; Ae[sgf+f+1][l4] = v.y;
      Ae[sgf+f+2][l4] = v.z; Ae[sgf+f+3][l4] = v.w;
    }
  }
  // stage Bc (centered gathered columns)
  {
    int jg = j0 + l4;
    if (jg < n){
      const float* Frow = featT + (size_t)idx[jg]*FEAT + sgf;
      const float* mp = miu + sgf;
      for (int f=0; f<64; f+=4){
        float4 v = *(const float4*)&Frow[f];
        Bc[sgf+f+0][l4] = v.x - mp[f+0];
        Bc[sgf+f+1][l4] = v.y - mp[f+1];
        Bc[sgf+f+2][l4] = v.z - mp[f+2];
        Bc[sgf+f+3][l4] = v.w - mp[f+3];
      }
    } else {
      for (int f=0; f<64; f++) Bc[sgf+f][l4] = 0.f;
    }
  }
  __syncthreads();
  int ti = t & 15, tj = t >> 4;   // ti: k-sub, tj: j-sub
  float acc[4][4] = {};
  for (int f=0; f<FEAT; f+=4){
    #pragma unroll
    for (int ff=0; ff<4; ff++){
      float4 av = *(const float4*)&Ae[f+ff][ti*4];
      float4 bv = *(const float4*)&Bc[f+ff][tj*4];
      float aa[4] = {av.x,av.y,av.z,av.w};
      float bb[4] = {bv.x,bv.y,bv.z,bv.w};
      #pragma unroll
      for (int kk=0;kk<4;kk++)
        #pragma unroll
        for (int jj=0;jj<4;jj++)
          acc[kk][jj] += aa[kk]*bb[jj];
    }
  }
  #pragma unroll
  for (int kk=0; kk<4; kk++){
    float4 o; o.x=acc[kk][0]; o.y=acc[kk][1]; o.z=acc[kk][2]; o.w=acc[kk][3];
    *(float4*)&Bg[(size_t)(kb + ti*4 + kk)*BCAP + j0 + tj*4] = o;
  }
}

// ---------------- fp GEMM (pm @ B) with fused m2/m4 + per-block loss partials ----------------
__global__ __launch_bounds__(256) void k_fp(const float* __restrict__ pm, float* ws){
  __shared__ float As[256][68];   // [k][i-local]  (pm tile, transposed)
  __shared__ float Bs[256][68];   // [k][j-local]
  __shared__ float ev[256];
  __shared__ float red[64][17];
  __shared__ float m2s[64];
  __shared__ float m4s[64];
  int c = blockIdx.y;
  int i0 = blockIdx.x*64;
  int n = ((int*)(ws+OFF_CNT))[c];
  float nf = fmaxf((float)n, 1.f);
  const float* evals = ws + OFF_EVAL + (size_t)c*FEAT;
  const float* Bg = ws + OFF_B + (size_t)c*FEAT*BCAP;
  int t = threadIdx.x;
  int l4 = t >> 2;
  // stage As
  {
    int sgf = (t & 3)*64;
    int gi = i0 + l4;
    if (gi < NDIR){
      const float* row = pm + (size_t)gi*FEAT + sgf;
      for (int f=0; f<64; f+=4){
        float4 v = *(const float4*)&row[f];
        As[sgf+f+0][l4] = v.x; As[sgf+f+1][l4] = v.y;
        As[sgf+f+2][l4] = v.z; As[sgf+f+3][l4] = v.w;
      }
    } else {
      for (int f=0; f<64; f++) As[sgf+f][l4] = 0.f;
    }
  }
  if (t < 256) ev[t] = evals[t];
  int ti = t & 15, tj = t >> 4;
  float s2[4] = {0.f,0.f,0.f,0.f};
  float s4[4] = {0.f,0.f,0.f,0.f};
  int nch = (n + 63)/64;
  int sgj = (t & 3)*16;
  for (int ch=0; ch<nch; ch++){
    int j0 = ch*64;
    __syncthreads();
    for (int g=0; g<4; g++){
      int r = l4 + 64*g;
      const float* Brow = Bg + (size_t)r*BCAP + j0 + sgj;
      #pragma unroll
      for (int e=0; e<16; e+=4){
        int j = j0 + sgj + e;
        float4 v;
        if (j + 3 < n) v = *(const float4*)&Brow[e];
        else {
          v.x = (j+0<n)? Brow[e+0] : 0.f;
          v.y = (j+1<n)? Brow[e+1] : 0.f;
          v.z = (j+2<n)? Brow[e+2] : 0.f;
          v.w = (j+3<n)? Brow[e+3] : 0.f;
        }
        *(float4*)&Bs[r][sgj+e] = v;
      }
    }
    __syncthreads();
    float acc[4][4] = {};
    for (int k=0; k<FEAT; k+=4){
      #pragma unroll
      for (int kk=0; kk<4; kk++){
        float4 av = *(const float4*)&As[k+kk][ti*4];
        float4 bv = *(const float4*)&Bs[k+kk][tj*4];
        float aa[4] = {av.x,av.y,av.z,av.w};
        float bb[4] = {bv.x,bv.y,bv.z,bv.w};
        #pragma unroll
        for (int ii=0;ii<4;ii++)
          #pragma unroll
          for (int jj=0;jj<4;jj++)
            acc[ii][jj] += aa[ii]*bb[jj];
      }
    }
    #pragma unroll
    for (int ii=0;ii<4;ii++){
      #pragma unroll
      for (int jj=0;jj<4;jj++){
        float v = acc[ii][jj];
        float v2 = v*v;
        s2[ii] += v2;
        s4[ii] += v2*v2;
      }
    }
  }
  __syncthreads();
  #pragma unroll
  for (int ii=0;ii<4;ii++) red[ti*4+ii][tj] = s2[ii];
  __syncthreads();
  if (t < 64){
    float s = 0.f;
    for (int u=0;u<16;u++) s += red[t][u];
    m2s[t] = s;
  }
  __syncthreads();
  #pragma unroll
  for (int ii=0;ii<4;ii++) red[ti*4+ii][tj] = s4[ii];
  __syncthreads();
  if (t < 64){
    float s = 0.f;
    for (int u=0;u<16;u++) s += red[t][u];
    m4s[t] = s;
  }
  __syncthreads();
  if (t < 64){
    float stds = 0.f;
    for (int k=0;k<FEAT;k++){
      float a = As[k][t];
      stds += a*a*ev[k];
    }
    int i = i0 + t;
    float l2 = 0.f, lk = 0.f;
    if (i < NDIR){
      float m2 = m2s[t]/(nf*stds);
      float m4 = m4s[t]/(nf*stds*stds);
      float d2 = m2 - 1.f;
      l2 = d2*d2;
      float dk = m4 - 3.f*m2*m2;
      lk = dk*dk;
    }
    #pragma unroll
    for (int o=1;o<64;o<<=1){
      l2 += __shfl_xor(l2, o);
      lk += __shfl_xor(lk, o);
    }
    if (t == 0){
      float* lp = ws + OFF_LPART + ((size_t)c*160 + blockIdx.x)*2;
      lp[0] = l2;
      lp[1] = lk;
    }
  }
}

// ---------------- final scalar (deterministic fixed-order reduction) ----------------
__global__ __launch_bounds__(64) void k_final(float* ws, float* out){
  int t = threadIdx.x;   // one wave
  const int* cnt = (const int*)(ws + OFF_CNT);
  const float* lp = ws + OFF_LPART;
  float tot = 0.f, an = 0.f;
  for (int c=0;c<NCLS;c++){
    float s2 = 0.f, sk = 0.f;
    for (int b=t; b<NBLK_FP; b+=64){
      s2 += lp[((size_t)c*160 + b)*2 + 0];
      sk += lp[((size_t)c*160 + b)*2 + 1];
    }
    #pragma unroll
    for (int o=1;o<64;o<<=1){
      s2 += __shfl_xor(s2, o);
      sk += __shfl_xor(sk, o);
    }
    if (cnt[c] > 0){
      tot += s2/(float)NDIR + sk/(float)NDIR;
      an += 1.f;
    }
  }
  if (t == 0) out[0] = tot / fmaxf(an, 1.f);
}

extern "C" void kernel_launch(void* const* d_in, const int* in_sizes, int n_in,
                              void* d_out, int out_size, void* d_ws, size_t ws_size,
                              hipStream_t stream) {
  const float* feat = (const float*)d_in[0];
  const int*   lab  = (const int*)d_in[1];
  const float* pm   = (const float*)d_in[2];
  float* out = (float*)d_out;
  float* ws  = (float*)d_ws;

  hipLaunchKernelGGL(k_transpose, dim3(HWPX/32, FEAT/32), dim3(32,8), 0, stream, feat, ws);
  hipLaunchKernelGGL(k_index,     dim3(1),            dim3(256),     0, stream, lab, ws);
  hipLaunchKernelGGL(k_miu_part,  dim3(32),           dim3(256),     0, stream, lab, ws);
  hipLaunchKernelGGL(k_miu_fin,   dim3(1),            dim3(1024),    0, stream, ws);
  hipLaunchKernelGGL(k_cov,       dim3(16, NCLS),     dim3(256),     0, stream, ws);
  hipLaunchKernelGGL(k_jacobi,    dim3(NCLS),         dim3(1024),    0, stream, ws);
  hipLaunchKernelGGL(k_bmat,      dim3(BCAP/64, 4, NCLS), dim3(256), 0, stream, ws);
  hipLaunchKernelGGL(k_fp,        dim3(NBLK_FP, NCLS), dim3(256),    0, stream, pm, ws);
  hipLaunchKernelGGL(k_final,     dim3(1),            dim3(64),      0, stream, ws, out);
}

// Round 7
// 17519.090 us; speedup vs baseline: 2.5294x; 1.3959x over previous
//
#include <hip/hip_runtime.h>
#include <cstdint>
#include <cstddef>

#define FEAT 256
#define HWPX 16384
#define NDIR 10000
#define NCLS 4          // classes 1..4
#define BCAP 4096       // per-class column capacity for B (n_c ~ 3277)
#define NSWO 7          // outer block-Jacobi sweeps (fixed, deterministic; 7*31 % 31 == 0)
#define JTOL 4e-12f     // skip rotation if d^2 <= na*nb*JTOL
#define NBLK_FP 157     // ceil(NDIR/64)

// ---- workspace layout (element offsets; 4B elements) ----
static const size_t OFF_FEATT = 0;                                // 16384*256 f32
static const size_t OFF_IDX   = OFF_FEATT + (size_t)HWPX*FEAT;    // 4*16384 int
static const size_t OFF_CNT   = OFF_IDX + (size_t)NCLS*HWPX;      // 4 int (+pad)
static const size_t OFF_MIU   = OFF_CNT + 64;                     // 4*256 f32
static const size_t OFF_MIUP  = OFF_MIU + (size_t)NCLS*FEAT;      // 32*4*256 f32 partials
static const size_t OFF_G     = OFF_MIUP + (size_t)32*NCLS*FEAT;  // 4*65536 f32
static const size_t OFF_ETS   = OFF_G + (size_t)NCLS*FEAT*FEAT;   // 4*65536 f32
static const size_t OFF_EVAL  = OFF_ETS + (size_t)NCLS*FEAT*FEAT; // 4*256 f32
static const size_t OFF_LPART = OFF_EVAL + (size_t)NCLS*FEAT;     // 4*160*2 f32 per-block partials
static const size_t OFF_B     = OFF_LPART + (size_t)NCLS*160*2;   // 4*256*BCAP f32
static const size_t OFF_XCH   = OFF_B + (size_t)NCLS*FEAT*BCAP;   // 4*2*32*2048 f32 transit
// total ~ 39 MB

// 64-lane sum, deterministic fixed order, result uniform (lands in SGPRs).
// 4 DPP row-rotate adds (16-lane allreduce) + 4 readlane + 3 scalar adds.
// NO LDS-pipe ops (previous __shfl_xor version went through ds_bpermute).
__device__ __forceinline__ float wsum64(float v){
  int x;
  x = __builtin_amdgcn_update_dpp(0, __float_as_int(v), 0x121, 0xF, 0xF, false); v += __int_as_float(x); // row_ror:1
  x = __builtin_amdgcn_update_dpp(0, __float_as_int(v), 0x122, 0xF, 0xF, false); v += __int_as_float(x); // row_ror:2
  x = __builtin_amdgcn_update_dpp(0, __float_as_int(v), 0x124, 0xF, 0xF, false); v += __int_as_float(x); // row_ror:4
  x = __builtin_amdgcn_update_dpp(0, __float_as_int(v), 0x128, 0xF, 0xF, false); v += __int_as_float(x); // row_ror:8
  float a = __int_as_float(__builtin_amdgcn_readlane(__float_as_int(v), 0));
  float b = __int_as_float(__builtin_amdgcn_readlane(__float_as_int(v), 16));
  float c = __int_as_float(__builtin_amdgcn_readlane(__float_as_int(v), 32));
  float d = __int_as_float(__builtin_amdgcn_readlane(__float_as_int(v), 48));
  return (a + b) + (c + d);
}

// ---------------- transpose feat (256 x 16384) -> featT (16384 x 256) ----------------
__global__ __launch_bounds__(256) void k_transpose(const float* __restrict__ feat, float* __restrict__ ws){
  __shared__ float tile[32][33];
  float* featT = ws + OFF_FEATT;
  int j0 = blockIdx.x*32, f0 = blockIdx.y*32;
  int tx = threadIdx.x, ty = threadIdx.y; // (32, 8)
  #pragma unroll
  for (int r=0;r<4;r++){
    int f = f0 + ty + r*8;
    tile[ty+r*8][tx] = feat[(size_t)f*HWPX + j0 + tx];
  }
  __syncthreads();
  #pragma unroll
  for (int r=0;r<4;r++){
    int j = j0 + ty + r*8;
    featT[(size_t)j*FEAT + f0 + tx] = tile[tx][ty+r*8];
  }
}

// ---------------- build compacted per-class index lists + counts ----------------
__global__ __launch_bounds__(256) void k_index(const int* __restrict__ lab, float* ws){
  __shared__ int sc[256];
  int* idx = (int*)(ws + OFF_IDX);
  int* cnt = (int*)(ws + OFF_CNT);
  int t = threadIdx.x;
  int base = t*64;
  for (int c=1;c<=NCLS;c++){
    __syncthreads();
    int m = 0;
    for (int k=0;k<64;k++) m += (lab[base+k]==c) ? 1 : 0;
    sc[t] = m;
    __syncthreads();
    for (int off=1; off<256; off<<=1){
      int v = (t>=off)? sc[t-off] : 0;
      __syncthreads();
      sc[t] += v;
      __syncthreads();
    }
    int pos = sc[t] - m;
    if (t==255) cnt[c-1] = sc[255];
    int* ic = idx + (size_t)(c-1)*HWPX;
    for (int k=0;k<64;k++){
      if (lab[base+k]==c) ic[pos++] = base+k;
    }
  }
}

// ---------------- per-class feature-sum partials (deterministic, no atomics) ----------------
__global__ __launch_bounds__(256) void k_miu_part(const int* __restrict__ lab, float* ws){
  const float* featT = ws + OFF_FEATT;
  float* part = ws + OFF_MIUP;
  int f = threadIdx.x;
  int b = blockIdx.x;
  int j0 = b*512;
  float a0=0.f,a1=0.f,a2=0.f,a3=0.f;
  for (int j=j0;j<j0+512;j++){
    float v = featT[(size_t)j*FEAT + f];
    int c = lab[j];
    a0 += (c==1)? v : 0.f;
    a1 += (c==2)? v : 0.f;
    a2 += (c==3)? v : 0.f;
    a3 += (c==4)? v : 0.f;
  }
  float* pb = part + (size_t)b*NCLS*FEAT;
  pb[0*FEAT+f] = a0;
  pb[1*FEAT+f] = a1;
  pb[2*FEAT+f] = a2;
  pb[3*FEAT+f] = a3;
}

__global__ __launch_bounds__(1024) void k_miu_fin(float* ws){
  int t = threadIdx.x;            // 0..1023 = c*FEAT+f
  int c = t / FEAT;
  const float* part = ws + OFF_MIUP;
  float s = 0.f;
  for (int b=0;b<32;b++) s += part[(size_t)b*NCLS*FEAT + t];   // fixed order
  int n = ((int*)(ws+OFF_CNT))[c];
  float nf = fmaxf((float)n, 1.f);
  ws[OFF_MIU + t] = s / nf;
}

// ---------------- cov per class (64x64 tiles): G = m2mat/n - miu miu^T + eps I ----------------
__global__ __launch_bounds__(256) void k_cov(float* ws){
  __shared__ float Xa[32][68];
  __shared__ float Xb[32][68];
  const float* featT = ws + OFF_FEATT;
  int c = blockIdx.y;
  const int* idx = (const int*)(ws + OFF_IDX) + (size_t)c*HWPX;
  int n = ((int*)(ws+OFF_CNT))[c];
  float nf = fmaxf((float)n,1.f);
  const float* miu = ws + OFF_MIU + (size_t)c*FEAT;
  float* G = ws + OFF_G + (size_t)c*FEAT*FEAT;
  int fb = (blockIdx.x & 3)*64, gb = (blockIdx.x >> 2)*64;
  int t = threadIdx.x;
  int ti = t & 15, tj = t >> 4;
  float acc[4][4] = {};
  int jr = t >> 3;         // 0..31
  int s8 = (t & 7) * 8;    // 0..56
  int nch = (n + 31)/32;
  for (int ch=0; ch<nch; ch++){
    int jg = ch*32 + jr;
    __syncthreads();
    if (jg < n){
      int jx = idx[jg];
      const float* row = featT + (size_t)jx*FEAT;
      #pragma unroll
      for (int k=0;k<8;k++){ Xa[jr][s8+k] = row[fb+s8+k]; Xb[jr][s8+k] = row[gb+s8+k]; }
    } else {
      #pragma unroll
      for (int k=0;k<8;k++){ Xa[jr][s8+k] = 0.f; Xb[jr][s8+k] = 0.f; }
    }
    __syncthreads();
    for (int jj=0;jj<32;jj++){
      float4 av = *(const float4*)&Xa[jj][ti*4];
      float4 bv = *(const float4*)&Xb[jj][tj*4];
      float aa[4] = {av.x,av.y,av.z,av.w};
      float bb[4] = {bv.x,bv.y,bv.z,bv.w};
      #pragma unroll
      for (int ii=0; ii<4; ii++)
        #pragma unroll
        for (int j2=0; j2<4; j2++)
          acc[ii][j2] += aa[ii]*bb[j2];
    }
  }
  float eps = fminf(fmaxf(1e-5f/nf, 1e-8f), 1e-5f);
  #pragma unroll
  for (int ii=0; ii<4; ii++){
    #pragma unroll
    for (int j2=0; j2<4; j2++){
      int f = fb + ti*4 + ii, g = gb + tj*4 + j2;
      float v = acc[ii][j2]/nf - miu[f]*miu[g] + ((f==g)? eps : 0.f);
      G[(size_t)g*FEAT + f] = v;   // column-major, col g
    }
  }
}

// ---------------- one-sided BLOCK Jacobi, scalarized static registers ----------------
// 32 groups of 8 columns. Wave w owns a group-pair (16 cols = 64 named floats);
// lane l owns rows 4l..4l+3. 120-pair sweep fully expanded, fast-math rotation
// scalars (rcp/rsq/sqrt single-instruction), no LDS ops in the hot loop.
// amdgpu_waves_per_eu(4,4): explicit MAX stops the compiler from chasing 8
// waves/EU (impossible with a 1024-thread block) and capping arch VGPRs at 64
// (which forced an AGPR split + accvgpr shuffling = the R6 VALU inflation).
__global__ void
__attribute__((amdgpu_flat_work_group_size(1024,1024), amdgpu_waves_per_eu(4,4)))
k_jacobi(float* ws){
  __shared__ float colsq[256];
  __shared__ int srt[256];
  __shared__ int inv_[256];
  int c = blockIdx.x;
  float* G = ws + OFF_G + (size_t)c*FEAT*FEAT;
  float* X = ws + OFF_XCH + (size_t)c*2*32*2048;
  int t = threadIdx.x;
  int lane = t & 63;
  int w = t >> 6;             // wave 0..15

#define FORJ16(M) M(0) M(1) M(2) M(3) M(4) M(5) M(6) M(7) M(8) M(9) M(10) M(11) M(12) M(13) M(14) M(15)
#define FORJ8L(M) M(0) M(1) M(2) M(3) M(4) M(5) M(6) M(7)
#define FORJ8H(M) M(8) M(9) M(10) M(11) M(12) M(13) M(14) M(15)

#define DECL(j) float C##j##x, C##j##y, C##j##z, C##j##w; float n##j;
  FORJ16(DECL)
#undef DECL

  int pg = (w==0)? 31 : w;        // initial (and final: NSWO*31 % 31 == 0) group ids
  int qg = (w==0)? 0  : 31 - w;

#define LDC(j) { float4 v_ = *(const float4*)&G[(size_t)(((j)<8)? (pg*8+(j)) : (qg*8+(j)-8))*FEAT + lane*4]; \
                 C##j##x=v_.x; C##j##y=v_.y; C##j##z=v_.z; C##j##w=v_.w; }
  FORJ16(LDC)
#undef LDC

#define NRMJ(j) n##j = wsum64(C##j##x*C##j##x + C##j##y*C##j##y + C##j##z*C##j##z + C##j##w*C##j##w);

#define ROT(ia, ib) { \
    float dp = C##ia##x*C##ib##x + C##ia##y*C##ib##y + C##ia##z*C##ib##z + C##ia##w*C##ib##w; \
    float d = wsum64(dp); \
    float na = n##ia, nb = n##ib; \
    if (d*d > na*nb*JTOL){ \
      float tau = (nb - na) * 0.5f * __builtin_amdgcn_rcpf(d); \
      float tt = copysignf(__builtin_amdgcn_rcpf(fabsf(tau) + __builtin_amdgcn_sqrtf(1.f + tau*tau)), tau); \
      float cc = __builtin_amdgcn_rsqf(1.f + tt*tt); \
      float sn = tt*cc; \
      float x_; \
      x_ = C##ia##x; C##ia##x = cc*x_ - sn*C##ib##x; C##ib##x = sn*x_ + cc*C##ib##x; \
      x_ = C##ia##y; C##ia##y = cc*x_ - sn*C##ib##y; C##ib##y = sn*x_ + cc*C##ib##y; \
      x_ = C##ia##z; C##ia##z = cc*x_ - sn*C##ib##z; C##ib##z = sn*x_ + cc*C##ib##z; \
      x_ = C##ia##w; C##ia##w = cc*x_ - sn*C##ib##w; C##ib##w = sn*x_ + cc*C##ib##w; \
      float cc2 = cc*cc, sn2 = sn*sn, csd = 2.f*cc*sn*d; \
      n##ia = cc2*na - csd + sn2*nb; \
      n##ib = sn2*na + csd + cc2*nb; \
    } \
  }

  for (int R=0; R<NSWO*31; R++){
    // exact column norms (refreshed each outer round; uniform across lanes)
    FORJ16(NRMJ)
    // inner sweep: all 120 pairs, round-robin tournament (m=0..14, k=0..7)
    ROT(15,0)  ROT(1,14)  ROT(2,13)  ROT(3,12)  ROT(4,11)  ROT(5,10)  ROT(6,9)   ROT(7,8)
    ROT(15,1)  ROT(2,0)   ROT(3,14)  ROT(4,13)  ROT(5,12)  ROT(6,11)  ROT(7,10)  ROT(8,9)
    ROT(15,2)  ROT(3,1)   ROT(4,0)   ROT(5,14)  ROT(6,13)  ROT(7,12)  ROT(8,11)  ROT(9,10)
    ROT(15,3)  ROT(4,2)   ROT(5,1)   ROT(6,0)   ROT(7,14)  ROT(8,13)  ROT(9,12)  ROT(10,11)
    ROT(15,4)  ROT(5,3)   ROT(6,2)   ROT(7,1)   ROT(8,0)   ROT(9,14)  ROT(10,13) ROT(11,12)
    ROT(15,5)  ROT(6,4)   ROT(7,3)   ROT(8,2)   ROT(9,1)   ROT(10,0)  ROT(11,14) ROT(12,13)
    ROT(15,6)  ROT(7,5)   ROT(8,4)   ROT(9,3)   ROT(10,2)  ROT(11,1)  ROT(12,0)  ROT(13,14)
    ROT(15,7)  ROT(8,6)   ROT(9,5)   ROT(10,4)  ROT(11,3)  ROT(12,2)  ROT(13,1)  ROT(14,0)
    ROT(15,8)  ROT(9,7)   ROT(10,6)  ROT(11,5)  ROT(12,4)  ROT(13,3)  ROT(14,2)  ROT(0,1)
    ROT(15,9)  ROT(10,8)  ROT(11,7)  ROT(12,6)  ROT(13,5)  ROT(14,4)  ROT(0,3)   ROT(1,2)
    ROT(15,10) ROT(11,9)  ROT(12,8)  ROT(13,7)  ROT(14,6)  ROT(0,5)   ROT(1,4)   ROT(2,3)
    ROT(15,11) ROT(12,10) ROT(13,9)  ROT(14,8)  ROT(0,7)   ROT(1,6)   ROT(2,5)   ROT(3,4)
    ROT(15,12) ROT(13,11) ROT(14,10) ROT(0,9)   ROT(1,8)   ROT(2,7)   ROT(3,6)   ROT(4,5)
    ROT(15,13) ROT(14,12) ROT(0,11)  ROT(1,10)  ROT(2,9)   ROT(3,8)   ROT(4,7)   ROT(5,6)
    ROT(15,14) ROT(0,13)  ROT(1,12)  ROT(2,11)  ROT(3,10)  ROT(4,9)   ROT(5,8)   ROT(6,7)

    // group transit (double-buffered global; one barrier per round)
    int par = R & 1;
    float* XB = X + (size_t)par*32*2048;
    if (w >= 1){
#define STP(j) { float4 v_; v_.x=C##j##x; v_.y=C##j##y; v_.z=C##j##z; v_.w=C##j##w; \
                 *(float4*)&XB[(size_t)w*2048 + (j)*256 + lane*4] = v_; }
      FORJ8L(STP)
#undef STP
    }
    if (w <= 14){
#define STQ(j) { float4 v_; v_.x=C##j##x; v_.y=C##j##y; v_.z=C##j##z; v_.w=C##j##w; \
                 *(float4*)&XB[(size_t)(16+w)*2048 + ((j)-8)*256 + lane*4] = v_; }
      FORJ8H(STQ)
#undef STQ
    }
    __syncthreads();
    if (w == 15){
#define MV(a,b) C##a##x=C##b##x; C##a##y=C##b##y; C##a##z=C##b##z; C##a##w=C##b##w;
      MV(0,8) MV(1,9) MV(2,10) MV(3,11) MV(4,12) MV(5,13) MV(6,14) MV(7,15)   // newP = own oldQ
#undef MV
#define LQ(j) { float4 v_ = *(const float4*)&XB[(size_t)(16+14)*2048 + ((j)-8)*256 + lane*4]; \
                C##j##x=v_.x; C##j##y=v_.y; C##j##z=v_.z; C##j##w=v_.w; }
      FORJ8H(LQ)                                                               // oldQ_14
#undef LQ
    } else if (w == 0){
#define LQ(j) { float4 v_ = *(const float4*)&XB[(size_t)1*2048 + ((j)-8)*256 + lane*4]; \
                C##j##x=v_.x; C##j##y=v_.y; C##j##z=v_.z; C##j##w=v_.w; }
      FORJ8H(LQ)                                                               // oldP_1
#undef LQ
    } else {
#define LP(j) { float4 v_ = *(const float4*)&XB[(size_t)(w+1)*2048 + (j)*256 + lane*4]; \
                C##j##x=v_.x; C##j##y=v_.y; C##j##z=v_.z; C##j##w=v_.w; }
      FORJ8L(LP)                                                               // oldP_{w+1}
#undef LP
#define LQ(j) { float4 v_ = *(const float4*)&XB[(size_t)(16+w-1)*2048 + ((j)-8)*256 + lane*4]; \
                C##j##x=v_.x; C##j##y=v_.y; C##j##z=v_.z; C##j##w=v_.w; }
      FORJ8H(LQ)                                                               // oldQ_{w-1}
#undef LQ
    }
  }

  // ---- extraction: exact norms, global rank-sort, normalized rows out ----
  FORJ16(NRMJ)
#define WCS(j) if (lane == (j)) colsq[((j)<8)? (pg*8+(j)) : (qg*8+(j)-8)] = n##j;
  FORJ16(WCS)
#undef WCS
  __syncthreads();
  if (t < 256){
    float my = colsq[t];
    int rk = 0;
    for (int u=0; u<256; u++){
      float cu = colsq[u];
      rk += ((cu > my) || (cu == my && u < t)) ? 1 : 0;
    }
    srt[rk] = t;
  }
  __syncthreads();
  float* evals = ws + OFF_EVAL + (size_t)c*FEAT;
  if (t < 256){
    evals[t] = sqrtf(colsq[srt[t]]);
    inv_[srt[t]] = t;
  }
  __syncthreads();
  float* Et = ws + OFF_ETS + (size_t)c*FEAT*FEAT;
#define WET(j) { \
    int cid = ((j)<8)? (pg*8+(j)) : (qg*8+(j)-8); \
    int rk = inv_[cid]; \
    float iv = 1.f / sqrtf(n##j); \
    float4 v_; v_.x=C##j##x*iv; v_.y=C##j##y*iv; v_.z=C##j##z*iv; v_.w=C##j##w*iv; \
    *(float4*)&Et[(size_t)rk*FEAT + lane*4] = v_; \
  }
  FORJ16(WET)
#undef WET
#undef ROT
#undef NRMJ
#undef FORJ16
#undef FORJ8L
#undef FORJ8H
}

// ---------------- B[c] = EtS (256x256, sorted) @ centered_gathered (256 x n_c) ----------------
__global__ __launch_bounds__(256) void k_bmat(float* ws){
  __shared__ float Ae[256][68];   // [f][k-local]
  __shared__ float Bc[256][68];   // [f][j-local]
  int c = blockIdx.z;
  int n = ((int*)(ws+OFF_CNT))[c];
  int j0 = blockIdx.x*64;
  if (j0 >= n) return;            // block-uniform
  int kb = blockIdx.y*64;
  const float* featT = ws + OFF_FEATT;
  const int* idx = (const int*)(ws + OFF_IDX) + (size_t)c*HWPX;
  const float* miu = ws + OFF_MIU + (size_t)c*FEAT;
  const float* Ets = ws + OFF_ETS + (size_t)c*FEAT*FEAT;
  float* Bg = ws + OFF_B + (size_t)c*FEAT*BCAP;
  int t = threadIdx.x;
  int l4 = t >> 2, sgf = (t & 3)*64;
  // stage Ae
  {
    const float* Erow = Ets + (size_t)(kb+l4)*FEAT + sgf;
    for (int f=0; f<64; f+=4){
      float4 v = *(const float4*)&Erow[f];
      Ae[sgf+f+0][l4] = v.x; Ae[sgf+f+1][l4] = v.y;
      Ae[sgf+f+2][l4] = v.z; Ae[sgf+f+3][l4] = v.w;
    }
  }
  // stage Bc (centered gathered columns)
  {
    int jg = j0 + l4;
    if (jg < n){
      const float* Frow = featT + (size_t)idx[jg]*FEAT + sgf;
      const float* mp = miu + sgf;
      for (int f=0; f<64; f+=4){
        float4 v = *(const float4*)&Frow[f];
        Bc[sgf+f+0][l4] = v.x - mp[f+0];
        Bc[sgf+f+1][l4] = v.y - mp[f+1];
        Bc[sgf+f+2][l4] = v.z - mp[f+2];
        Bc[sgf+f+3][l4] = v.w - mp[f+3];
      }
    } else {
      for (int f=0; f<64; f++) Bc[sgf+f][l4] = 0.f;
    }
  }
  __syncthreads();
  int ti = t & 15, tj = t >> 4;   // ti: k-sub, tj: j-sub
  float acc[4][4] = {};
  for (int f=0; f<FEAT; f+=4){
    #pragma unroll
    for (int ff=0; ff<4; ff++){
      float4 av = *(const float4*)&Ae[f+ff][ti*4];
      float4 bv = *(const float4*)&Bc[f+ff][tj*4];
      float aa[4] = {av.x,av.y,av.z,av.w};
      float bb[4] = {bv.x,bv.y,bv.z,bv.w};
      #pragma unroll
      for (int kk=0;kk<4;kk++)
        #pragma unroll
        for (int jj=0;jj<4;jj++)
          acc[kk][jj] += aa[kk]*bb[jj];
    }
  }
  #pragma unroll
  for (int kk=0; kk<4; kk++){
    float4 o; o.x=acc[kk][0]; o.y=acc[kk][1]; o.z=acc[kk][2]; o.w=acc[kk][3];
    *(float4*)&Bg[(size_t)(kb + ti*4 + kk)*BCAP + j0 + tj*4] = o;
  }
}

// ---------------- fp GEMM (pm @ B) with fused m2/m4 + per-block loss partials ----------------
__global__ __launch_bounds__(256) void k_fp(const float* __restrict__ pm, float* ws){
  __shared__ float As[256][68];   // [k][i-local]  (pm tile, transposed)
  __shared__ float Bs[256][68];   // [k][j-local]
  __shared__ float ev[256];
  __shared__ float red[64][17];
  __shared__ float m2s[64];
  __shared__ float m4s[64];
  int c = blockIdx.y;
  int i0 = blockIdx.x*64;
  int n = ((int*)(ws+OFF_CNT))[c];
  float nf = fmaxf((float)n, 1.f);
  const float* evals = ws + OFF_EVAL + (size_t)c*FEAT;
  const float* Bg = ws + OFF_B + (size_t)c*FEAT*BCAP;
  int t = threadIdx.x;
  int l4 = t >> 2;
  // stage As
  {
    int sgf = (t & 3)*64;
    int gi = i0 + l4;
    if (gi < NDIR){
      const float* row = pm + (size_t)gi*FEAT + sgf;
      for (int f=0; f<64; f+=4){
        float4 v = *(const float4*)&row[f];
        As[sgf+f+0][l4] = v.x; As[sgf+f+1][l4] = v.y;
        As[sgf+f+2][l4] = v.z; As[sgf+f+3][l4] = v.w;
      }
    } else {
      for (int f=0; f<64; f++) As[sgf+f][l4] = 0.f;
    }
  }
  if (t < 256) ev[t] = evals[t];
  int ti = t & 15, tj = t >> 4;
  float s2[4] = {0.f,0.f,0.f,0.f};
  float s4[4] = {0.f,0.f,0.f,0.f};
  int nch = (n + 63)/64;
  int sgj = (t & 3)*16;
  for (int ch=0; ch<nch; ch++){
    int j0 = ch*64;
    __syncthreads();
    for (int g=0; g<4; g++){
      int r = l4 + 64*g;
      const float* Brow = Bg + (size_t)r*BCAP + j0 + sgj;
      #pragma unroll
      for (int e=0; e<16; e+=4){
        int j = j0 + sgj + e;
        float4 v;
        if (j + 3 < n) v = *(const float4*)&Brow[e];
        else {
          v.x = (j+0<n)? Brow[e+0] : 0.f;
          v.y = (j+1<n)? Brow[e+1] : 0.f;
          v.z = (j+2<n)? Brow[e+2] : 0.f;
          v.w = (j+3<n)? Brow[e+3] : 0.f;
        }
        *(float4*)&Bs[r][sgj+e] = v;
      }
    }
    __syncthreads();
    float acc[4][4] = {};
    for (int k=0; k<FEAT; k+=4){
      #pragma unroll
      for (int kk=0; kk<4; kk++){
        float4 av = *(const float4*)&As[k+kk][ti*4];
        float4 bv = *(const float4*)&Bs[k+kk][tj*4];
        float aa[4] = {av.x,av.y,av.z,av.w};
        float bb[4] = {bv.x,bv.y,bv.z,bv.w};
        #pragma unroll
        for (int ii=0;ii<4;ii++)
          #pragma unroll
          for (int jj=0;jj<4;jj++)
            acc[ii][jj] += aa[ii]*bb[jj];
      }
    }
    #pragma unroll
    for (int ii=0;ii<4;ii++){
      #pragma unroll
      for (int jj=0;jj<4;jj++){
        float v = acc[ii][jj];
        float v2 = v*v;
        s2[ii] += v2;
        s4[ii] += v2*v2;
      }
    }
  }
  __syncthreads();
  #pragma unroll
  for (int ii=0;ii<4;ii++) red[ti*4+ii][tj] = s2[ii];
  __syncthreads();
  if (t < 64){
    float s = 0.f;
    for (int u=0;u<16;u++) s += red[t][u];
    m2s[t] = s;
  }
  __syncthreads();
  #pragma unroll
  for (int ii=0;ii<4;ii++) red[ti*4+ii][tj] = s4[ii];
  __syncthreads();
  if (t < 64){
    float s = 0.f;
    for (int u=0;u<16;u++) s += red[t][u];
    m4s[t] = s;
  }
  __syncthreads();
  if (t < 64){
    float stds = 0.f;
    for (int k=0;k<FEAT;k++){
      float a = As[k][t];
      stds += a*a*ev[k];
    }
    int i = i0 + t;
    float l2 = 0.f, lk = 0.f;
    if (i < NDIR){
      float m2 = m2s[t]/(nf*stds);
      float m4 = m4s[t]/(nf*stds*stds);
      float d2 = m2 - 1.f;
      l2 = d2*d2;
      float dk = m4 - 3.f*m2*m2;
      lk = dk*dk;
    }
    #pragma unroll
    for (int o=1;o<64;o<<=1){
      l2 += __shfl_xor(l2, o);
      lk += __shfl_xor(lk, o);
    }
    if (t == 0){
      float* lp = ws + OFF_LPART + ((size_t)c*160 + blockIdx.x)*2;
      lp[0] = l2;
      lp[1] = lk;
    }
  }
}

// ---------------- final scalar (deterministic fixed-order reduction) ----------------
__global__ __launch_bounds__(64) void k_final(float* ws, float* out){
  int t = threadIdx.x;   // one wave
  const int* cnt = (const int*)(ws + OFF_CNT);
  const float* lp = ws + OFF_LPART;
  float tot = 0.f, an = 0.f;
  for (int c=0;c<NCLS;c++){
    float s2 = 0.f, sk = 0.f;
    for (int b=t; b<NBLK_FP; b+=64){
      s2 += lp[((size_t)c*160 + b)*2 + 0];
      sk += lp[((size_t)c*160 + b)*2 + 1];
    }
    #pragma unroll
    for (int o=1;o<64;o<<=1){
      s2 += __shfl_xor(s2, o);
      sk += __shfl_xor(sk, o);
    }
    if (cnt[c] > 0){
      tot += s2/(float)NDIR + sk/(float)NDIR;
      an += 1.f;
    }
  }
  if (t == 0) out[0] = tot / fmaxf(an, 1.f);
}

extern "C" void kernel_launch(void* const* d_in, const int* in_sizes, int n_in,
                              void* d_out, int out_size, void* d_ws, size_t ws_size,
                              hipStream_t stream) {
  const float* feat = (const float*)d_in[0];
  const int*   lab  = (const int*)d_in[1];
  const float* pm   = (const float*)d_in[2];
  float* out = (float*)d_out;
  float* ws  = (float*)d_ws;

  hipLaunchKernelGGL(k_transpose, dim3(HWPX/32, FEAT/32), dim3(32,8), 0, stream, feat, ws);
  hipLaunchKernelGGL(k_index,     dim3(1),            dim3(256),     0, stream, lab, ws);
  hipLaunchKernelGGL(k_miu_part,  dim3(32),           dim3(256),     0, stream, lab, ws);
  hipLaunchKernelGGL(k_miu_fin,   dim3(1),            dim3(1024),    0, stream, ws);
  hipLaunchKernelGGL(k_cov,       dim3(16, NCLS),     dim3(256),     0, stream, ws);
  hipLaunchKernelGGL(k_jacobi,    dim3(NCLS),         dim3(1024),    0, stream, ws);
  hipLaunchKernelGGL(k_bmat,      dim3(BCAP/64, 4, NCLS), dim3(256), 0, stream, ws);
  hipLaunchKernelGGL(k_fp,        dim3(NBLK_FP, NCLS), dim3(256),    0, stream, pm, ws);
  hipLaunchKernelGGL(k_final,     dim3(1),            dim3(64),      0, stream, ws, out);
}

// Round 8
// 14067.618 us; speedup vs baseline: 3.1500x; 1.2453x over previous
//
#include <hip/hip_runtime.h>
#include <cstdint>
#include <cstddef>

#define FEAT 256
#define HWPX 16384
#define NDIR 10000
#define NCLS 4          // classes 1..4
#define BCAP 4096       // per-class column capacity for B (n_c ~ 3277)
#define NSWO 7          // outer block-Jacobi sweeps (fixed, deterministic; 7*31 % 31 == 0)
#define JTOL 4e-12f     // skip rotation if d^2 <= na*nb*JTOL
#define NBLK_FP 157     // ceil(NDIR/64)

// ---- workspace layout (element offsets; 4B elements) ----
static const size_t OFF_FEATT = 0;                                // 16384*256 f32
static const size_t OFF_IDX   = OFF_FEATT + (size_t)HWPX*FEAT;    // 4*16384 int
static const size_t OFF_CNT   = OFF_IDX + (size_t)NCLS*HWPX;      // 4 int (+pad)
static const size_t OFF_MIU   = OFF_CNT + 64;                     // 4*256 f32
static const size_t OFF_MIUP  = OFF_MIU + (size_t)NCLS*FEAT;      // 32*4*256 f32 partials
static const size_t OFF_G     = OFF_MIUP + (size_t)32*NCLS*FEAT;  // 4*65536 f32
static const size_t OFF_ETS   = OFF_G + (size_t)NCLS*FEAT*FEAT;   // 4*65536 f32
static const size_t OFF_EVAL  = OFF_ETS + (size_t)NCLS*FEAT*FEAT; // 4*256 f32
static const size_t OFF_LPART = OFF_EVAL + (size_t)NCLS*FEAT;     // 4*160*2 f32 per-block partials
static const size_t OFF_B     = OFF_LPART + (size_t)NCLS*160*2;   // 4*256*BCAP f32
static const size_t OFF_XCH   = OFF_B + (size_t)NCLS*FEAT*BCAP;   // 4*2*32*2048 f32 transit
// total ~ 39 MB

// 64-lane sum, deterministic fixed order, result uniform.
// 4 DPP row-rotate adds (16-lane allreduce) + 4 readlane + 3 adds.
__device__ __forceinline__ float wsum64(float v){
  int x;
  x = __builtin_amdgcn_update_dpp(0, __float_as_int(v), 0x121, 0xF, 0xF, false); v += __int_as_float(x); // row_ror:1
  x = __builtin_amdgcn_update_dpp(0, __float_as_int(v), 0x122, 0xF, 0xF, false); v += __int_as_float(x); // row_ror:2
  x = __builtin_amdgcn_update_dpp(0, __float_as_int(v), 0x124, 0xF, 0xF, false); v += __int_as_float(x); // row_ror:4
  x = __builtin_amdgcn_update_dpp(0, __float_as_int(v), 0x128, 0xF, 0xF, false); v += __int_as_float(x); // row_ror:8
  float a = __int_as_float(__builtin_amdgcn_readlane(__float_as_int(v), 0));
  float b = __int_as_float(__builtin_amdgcn_readlane(__float_as_int(v), 16));
  float c = __int_as_float(__builtin_amdgcn_readlane(__float_as_int(v), 32));
  float d = __int_as_float(__builtin_amdgcn_readlane(__float_as_int(v), 48));
  return (a + b) + (c + d);
}

// ---------------- transpose feat (256 x 16384) -> featT (16384 x 256) ----------------
__global__ __launch_bounds__(256) void k_transpose(const float* __restrict__ feat, float* __restrict__ ws){
  __shared__ float tile[32][33];
  float* featT = ws + OFF_FEATT;
  int j0 = blockIdx.x*32, f0 = blockIdx.y*32;
  int tx = threadIdx.x, ty = threadIdx.y; // (32, 8)
  #pragma unroll
  for (int r=0;r<4;r++){
    int f = f0 + ty + r*8;
    tile[ty+r*8][tx] = feat[(size_t)f*HWPX + j0 + tx];
  }
  __syncthreads();
  #pragma unroll
  for (int r=0;r<4;r++){
    int j = j0 + ty + r*8;
    featT[(size_t)j*FEAT + f0 + tx] = tile[tx][ty+r*8];
  }
}

// ---------------- build compacted per-class index lists + counts ----------------
__global__ __launch_bounds__(256) void k_index(const int* __restrict__ lab, float* ws){
  __shared__ int sc[256];
  int* idx = (int*)(ws + OFF_IDX);
  int* cnt = (int*)(ws + OFF_CNT);
  int t = threadIdx.x;
  int base = t*64;
  for (int c=1;c<=NCLS;c++){
    __syncthreads();
    int m = 0;
    for (int k=0;k<64;k++) m += (lab[base+k]==c) ? 1 : 0;
    sc[t] = m;
    __syncthreads();
    for (int off=1; off<256; off<<=1){
      int v = (t>=off)? sc[t-off] : 0;
      __syncthreads();
      sc[t] += v;
      __syncthreads();
    }
    int pos = sc[t] - m;
    if (t==255) cnt[c-1] = sc[255];
    int* ic = idx + (size_t)(c-1)*HWPX;
    for (int k=0;k<64;k++){
      if (lab[base+k]==c) ic[pos++] = base+k;
    }
  }
}

// ---------------- per-class feature-sum partials (deterministic, no atomics) ----------------
__global__ __launch_bounds__(256) void k_miu_part(const int* __restrict__ lab, float* ws){
  const float* featT = ws + OFF_FEATT;
  float* part = ws + OFF_MIUP;
  int f = threadIdx.x;
  int b = blockIdx.x;
  int j0 = b*512;
  float a0=0.f,a1=0.f,a2=0.f,a3=0.f;
  for (int j=j0;j<j0+512;j++){
    float v = featT[(size_t)j*FEAT + f];
    int c = lab[j];
    a0 += (c==1)? v : 0.f;
    a1 += (c==2)? v : 0.f;
    a2 += (c==3)? v : 0.f;
    a3 += (c==4)? v : 0.f;
  }
  float* pb = part + (size_t)b*NCLS*FEAT;
  pb[0*FEAT+f] = a0;
  pb[1*FEAT+f] = a1;
  pb[2*FEAT+f] = a2;
  pb[3*FEAT+f] = a3;
}

__global__ __launch_bounds__(1024) void k_miu_fin(float* ws){
  int t = threadIdx.x;            // 0..1023 = c*FEAT+f
  int c = t / FEAT;
  const float* part = ws + OFF_MIUP;
  float s = 0.f;
  for (int b=0;b<32;b++) s += part[(size_t)b*NCLS*FEAT + t];   // fixed order
  int n = ((int*)(ws+OFF_CNT))[c];
  float nf = fmaxf((float)n, 1.f);
  ws[OFF_MIU + t] = s / nf;
}

// ---------------- cov per class (64x64 tiles): G = m2mat/n - miu miu^T + eps I ----------------
__global__ __launch_bounds__(256) void k_cov(float* ws){
  __shared__ float Xa[32][68];
  __shared__ float Xb[32][68];
  const float* featT = ws + OFF_FEATT;
  int c = blockIdx.y;
  const int* idx = (const int*)(ws + OFF_IDX) + (size_t)c*HWPX;
  int n = ((int*)(ws+OFF_CNT))[c];
  float nf = fmaxf((float)n,1.f);
  const float* miu = ws + OFF_MIU + (size_t)c*FEAT;
  float* G = ws + OFF_G + (size_t)c*FEAT*FEAT;
  int fb = (blockIdx.x & 3)*64, gb = (blockIdx.x >> 2)*64;
  int t = threadIdx.x;
  int ti = t & 15, tj = t >> 4;
  float acc[4][4] = {};
  int jr = t >> 3;         // 0..31
  int s8 = (t & 7) * 8;    // 0..56
  int nch = (n + 31)/32;
  for (int ch=0; ch<nch; ch++){
    int jg = ch*32 + jr;
    __syncthreads();
    if (jg < n){
      int jx = idx[jg];
      const float* row = featT + (size_t)jx*FEAT;
      #pragma unroll
      for (int k=0;k<8;k++){ Xa[jr][s8+k] = row[fb+s8+k]; Xb[jr][s8+k] = row[gb+s8+k]; }
    } else {
      #pragma unroll
      for (int k=0;k<8;k++){ Xa[jr][s8+k] = 0.f; Xb[jr][s8+k] = 0.f; }
    }
    __syncthreads();
    for (int jj=0;jj<32;jj++){
      float4 av = *(const float4*)&Xa[jj][ti*4];
      float4 bv = *(const float4*)&Xb[jj][tj*4];
      float aa[4] = {av.x,av.y,av.z,av.w};
      float bb[4] = {bv.x,bv.y,bv.z,bv.w};
      #pragma unroll
      for (int ii=0; ii<4; ii++)
        #pragma unroll
        for (int j2=0; j2<4; j2++)
          acc[ii][j2] += aa[ii]*bb[j2];
    }
  }
  float eps = fminf(fmaxf(1e-5f/nf, 1e-8f), 1e-5f);
  #pragma unroll
  for (int ii=0; ii<4; ii++){
    #pragma unroll
    for (int j2=0; j2<4; j2++){
      int f = fb + ti*4 + ii, g = gb + tj*4 + j2;
      float v = acc[ii][j2]/nf - miu[f]*miu[g] + ((f==g)? eps : 0.f);
      G[(size_t)g*FEAT + f] = v;   // column-major, col g
    }
  }
}

// ---------------- one-sided BLOCK Jacobi, P-in-registers / Q-in-LDS ----------------
// Register pressure fix: only the P-group (8 cols = 32 floats) + 16 norms live in
// registers (~56 live values, fits the allocator's 64-VGPR budget -> no AGPR
// shuffling). Q-group (cols 8..15) lives in LDS: 17 slots x 8KB; Q transit is a
// pure slot-index rotation (q_slot(w,R)=(w-R) mod 17, free slot rotates too).
// P transit via global parity buffer. One barrier per round. Rotation order and
// arithmetic are BIT-IDENTICAL to the R7 kernel (storage location only).
__global__ void
__attribute__((amdgpu_flat_work_group_size(1024,1024), amdgpu_waves_per_eu(4,4)))
k_jacobi(float* ws){
  __shared__ float QS[17*2048];   // 17 slots x (8 cols x 256 floats) = 139264 B
  __shared__ float colsq[256];
  __shared__ int srt[256];
  __shared__ int inv_[256];
  int c = blockIdx.x;
  float* G = ws + OFF_G + (size_t)c*FEAT*FEAT;
  float* X = ws + OFF_XCH + (size_t)c*2*32*2048;
  int t = threadIdx.x;
  int lane = t & 63;
  int lane4 = lane*4;
  int w = t >> 6;             // wave 0..15

#define FORJ8L(M) M(0) M(1) M(2) M(3) M(4) M(5) M(6) M(7)
#define FORJ8H(M) M(8) M(9) M(10) M(11) M(12) M(13) M(14) M(15)

  // P columns (group pg), named scalars
#define DECL(j) float C##j##x, C##j##y, C##j##z, C##j##w;
  FORJ8L(DECL)
#undef DECL
  float n0,n1,n2,n3,n4,n5,n6,n7,n8,n9,n10,n11,n12,n13,n14,n15;

  int pg = (w==0)? 31 : w;        // initial (and final) group ids
  int qg = (w==0)? 0  : 31 - w;

  int qslot = w;                  // this wave's Q slot
  int freeslot = 16;              // the idle slot (wave 1 writes into it each round)
  int qbase = qslot*2048 + lane4;

  // initial load: P -> regs, Q -> own LDS slot
#define LDP(j) { float4 v_ = *(const float4*)&G[(size_t)(pg*8+(j))*FEAT + lane4]; \
                 C##j##x=v_.x; C##j##y=v_.y; C##j##z=v_.z; C##j##w=v_.w; }
  FORJ8L(LDP)
#undef LDP
#define LDQ(j) { float4 v_ = *(const float4*)&G[(size_t)(qg*8+((j)-8))*FEAT + lane4]; \
                 *(float4*)&QS[qbase + ((j)-8)*256] = v_; }
  FORJ8H(LDQ)
#undef LDQ

  // storage accessors (global column id 0..15; 0..7 = P regs, 8..15 = Q LDS)
#define RP(g,ax,ay,az,aw) ax=C##g##x; ay=C##g##y; az=C##g##z; aw=C##g##w;
#define WP(g,ax,ay,az,aw) C##g##x=ax; C##g##y=ay; C##g##z=az; C##g##w=aw;
#define RQ(g,ax,ay,az,aw) { const float4 q_ = *(const float4*)&QS[qbase + ((g)-8)*256]; \
                            ax=q_.x; ay=q_.y; az=q_.z; aw=q_.w; }
#define WQ(g,ax,ay,az,aw) { float4 q_; q_.x=ax; q_.y=ay; q_.z=az; q_.w=aw; \
                            *(float4*)&QS[qbase + ((g)-8)*256] = q_; }

#define NRMP(j) n##j = wsum64(C##j##x*C##j##x + C##j##y*C##j##y + C##j##z*C##j##z + C##j##w*C##j##w);
#define NRMQ(j) { float ax,ay,az,aw; RQ(j,ax,ay,az,aw) \
                  n##j = wsum64(ax*ax + ay*ay + az*az + aw*aw); }

#define ROTG(LA,SA,ga,LB,SB,gb) { \
    float ax,ay,az,aw,bx,by,bz,bw; \
    LA(ga,ax,ay,az,aw) \
    LB(gb,bx,by,bz,bw) \
    float dp = ax*bx + ay*by + az*bz + aw*bw; \
    float d = wsum64(dp); \
    float na = n##ga, nb = n##gb; \
    if (d*d > na*nb*JTOL){ \
      float tau = (nb - na) * 0.5f * __builtin_amdgcn_rcpf(d); \
      float tt = copysignf(__builtin_amdgcn_rcpf(fabsf(tau) + __builtin_amdgcn_sqrtf(1.f + tau*tau)), tau); \
      float cc = __builtin_amdgcn_rsqf(1.f + tt*tt); \
      float sn = tt*cc; \
      float x_; \
      x_ = ax; ax = cc*x_ - sn*bx; bx = sn*x_ + cc*bx; \
      x_ = ay; ay = cc*x_ - sn*by; by = sn*x_ + cc*by; \
      x_ = az; az = cc*x_ - sn*bz; bz = sn*x_ + cc*bz; \
      x_ = aw; aw = cc*x_ - sn*bw; bw = sn*x_ + cc*bw; \
      float cc2 = cc*cc, sn2 = sn*sn, csd = 2.f*cc*sn*d; \
      n##ga = cc2*na - csd + sn2*nb; \
      n##gb = sn2*na + csd + cc2*nb; \
      SA(ga,ax,ay,az,aw) \
      SB(gb,bx,by,bz,bw) \
    } \
  }
#define ROT_PP(a,b) ROTG(RP,WP,a,RP,WP,b)
#define ROT_PQ(a,b) ROTG(RP,WP,a,RQ,WQ,b)
#define ROT_QP(a,b) ROTG(RQ,WQ,a,RP,WP,b)
#define ROT_QQ(a,b) ROTG(RQ,WQ,a,RQ,WQ,b)

  for (int R=0; R<NSWO*31; R++){
    // exact column norms (refreshed each outer round; uniform across lanes)
    NRMP(0) NRMP(1) NRMP(2) NRMP(3) NRMP(4) NRMP(5) NRMP(6) NRMP(7)
    NRMQ(8) NRMQ(9) NRMQ(10) NRMQ(11) NRMQ(12) NRMQ(13) NRMQ(14) NRMQ(15)
    // inner sweep: all 120 pairs, same tournament order as R7 (bit-identical)
    ROT_QP(15,0)  ROT_PQ(1,14)  ROT_PQ(2,13)  ROT_PQ(3,12)  ROT_PQ(4,11)  ROT_PQ(5,10)  ROT_PQ(6,9)   ROT_PQ(7,8)
    ROT_QP(15,1)  ROT_PP(2,0)   ROT_PQ(3,14)  ROT_PQ(4,13)  ROT_PQ(5,12)  ROT_PQ(6,11)  ROT_PQ(7,10)  ROT_QQ(8,9)
    ROT_QP(15,2)  ROT_PP(3,1)   ROT_PP(4,0)   ROT_PQ(5,14)  ROT_PQ(6,13)  ROT_PQ(7,12)  ROT_QQ(8,11)  ROT_QQ(9,10)
    ROT_QP(15,3)  ROT_PP(4,2)   ROT_PP(5,1)   ROT_PP(6,0)   ROT_PQ(7,14)  ROT_QQ(8,13)  ROT_QQ(9,12)  ROT_QQ(10,11)
    ROT_QP(15,4)  ROT_PP(5,3)   ROT_PP(6,2)   ROT_PP(7,1)   ROT_QP(8,0)   ROT_QQ(9,14)  ROT_QQ(10,13) ROT_QQ(11,12)
    ROT_QP(15,5)  ROT_PP(6,4)   ROT_PP(7,3)   ROT_QP(8,2)   ROT_QP(9,1)   ROT_QP(10,0)  ROT_QQ(11,14) ROT_QQ(12,13)
    ROT_QP(15,6)  ROT_PP(7,5)   ROT_QP(8,4)   ROT_QP(9,3)   ROT_QP(10,2)  ROT_QP(11,1)  ROT_QP(12,0)  ROT_QQ(13,14)
    ROT_QP(15,7)  ROT_QP(8,6)   ROT_QP(9,5)   ROT_QP(10,4)  ROT_QP(11,3)  ROT_QP(12,2)  ROT_QP(13,1)  ROT_QP(14,0)
    ROT_QQ(15,8)  ROT_QP(9,7)   ROT_QP(10,6)  ROT_QP(11,5)  ROT_QP(12,4)  ROT_QP(13,3)  ROT_QP(14,2)  ROT_PP(0,1)
    ROT_QQ(15,9)  ROT_QQ(10,8)  ROT_QP(11,7)  ROT_QP(12,6)  ROT_QP(13,5)  ROT_QP(14,4)  ROT_PP(0,3)   ROT_PP(1,2)
    ROT_QQ(15,10) ROT_QQ(11,9)  ROT_QQ(12,8)  ROT_QP(13,7)  ROT_QP(14,6)  ROT_PP(0,5)   ROT_PP(1,4)   ROT_PP(2,3)
    ROT_QQ(15,11) ROT_QQ(12,10) ROT_QQ(13,9)  ROT_QQ(14,8)  ROT_PP(0,7)   ROT_PP(1,6)   ROT_PP(2,5)   ROT_PP(3,4)
    ROT_QQ(15,12) ROT_QQ(13,11) ROT_QQ(14,10) ROT_PQ(0,9)   ROT_PQ(1,8)   ROT_PP(2,7)   ROT_PP(3,6)   ROT_PP(4,5)
    ROT_QQ(15,13) ROT_QQ(14,12) ROT_PQ(0,11)  ROT_PQ(1,10)  ROT_PQ(2,9)   ROT_PQ(3,8)   ROT_PP(4,7)   ROT_PP(5,6)
    ROT_QQ(15,14) ROT_PQ(0,13)  ROT_PQ(1,12)  ROT_PQ(2,11)  ROT_PQ(3,10)  ROT_PQ(4,9)   ROT_PQ(5,8)   ROT_PP(6,7)

    // ---- transit: P via global parity buffer; Q via LDS slot rotation ----
    int par = R & 1;
    float* XB = X + (size_t)par*32*2048;
    if (w >= 2){
#define STP(j) { float4 v_; v_.x=C##j##x; v_.y=C##j##y; v_.z=C##j##z; v_.w=C##j##w; \
                 *(float4*)&XB[(size_t)w*2048 + (j)*256 + lane4] = v_; }
      FORJ8L(STP)
#undef STP
    }
    if (w == 1){
      // oldP_1 becomes wave 0's newQ: write into the free LDS slot
      int fb_ = freeslot*2048 + lane4;
#define STF(j) { float4 v_; v_.x=C##j##x; v_.y=C##j##y; v_.z=C##j##z; v_.w=C##j##w; \
                 *(float4*)&QS[fb_ + (j)*256] = v_; }
      FORJ8L(STF)
#undef STF
    }
    if (w == 15){
      // newP_15 = own oldQ (read own slot pre-barrier; safe, wave-private)
#define LPQ(j) { const float4 q_ = *(const float4*)&QS[qbase + (j)*256]; \
                 C##j##x=q_.x; C##j##y=q_.y; C##j##z=q_.z; C##j##w=q_.w; }
      FORJ8L(LPQ)
#undef LPQ
    }
    __syncthreads();
    if (w >= 1 && w <= 14){
#define LP(j) { float4 v_ = *(const float4*)&XB[(size_t)(w+1)*2048 + (j)*256 + lane4]; \
                C##j##x=v_.x; C##j##y=v_.y; C##j##z=v_.z; C##j##w=v_.w; }
      FORJ8L(LP)                                                   // newP_w = oldP_{w+1}
#undef LP
    }
    // slot rotation: newQ_w = oldQ_{w-1}; wave0 adopts the just-written free slot
    qslot += 16; if (qslot >= 17) qslot -= 17;
    freeslot += 16; if (freeslot >= 17) freeslot -= 17;
    qbase = qslot*2048 + lane4;
  }

  // ---- extraction: exact norms, global rank-sort, normalized rows out ----
  NRMP(0) NRMP(1) NRMP(2) NRMP(3) NRMP(4) NRMP(5) NRMP(6) NRMP(7)
  NRMQ(8) NRMQ(9) NRMQ(10) NRMQ(11) NRMQ(12) NRMQ(13) NRMQ(14) NRMQ(15)
#define WCS(j) if (lane == (j)) colsq[((j)<8)? (pg*8+(j)) : (qg*8+(j)-8)] = n##j;
  FORJ8L(WCS) FORJ8H(WCS)
#undef WCS
  __syncthreads();
  if (t < 256){
    float my = colsq[t];
    int rk = 0;
    for (int u=0; u<256; u++){
      float cu = colsq[u];
      rk += ((cu > my) || (cu == my && u < t)) ? 1 : 0;
    }
    srt[rk] = t;
  }
  __syncthreads();
  float* evals = ws + OFF_EVAL + (size_t)c*FEAT;
  if (t < 256){
    evals[t] = sqrtf(colsq[srt[t]]);
    inv_[srt[t]] = t;
  }
  __syncthreads();
  float* Et = ws + OFF_ETS + (size_t)c*FEAT*FEAT;
#define WETP(j) { \
    int rk = inv_[pg*8+(j)]; \
    float iv = 1.f / sqrtf(n##j); \
    float4 v_; v_.x=C##j##x*iv; v_.y=C##j##y*iv; v_.z=C##j##z*iv; v_.w=C##j##w*iv; \
    *(float4*)&Et[(size_t)rk*FEAT + lane4] = v_; \
  }
  FORJ8L(WETP)
#undef WETP
#define WETQ(j) { \
    int rk = inv_[qg*8+(j)-8]; \
    float iv = 1.f / sqrtf(n##j); \
    const float4 q_ = *(const float4*)&QS[qbase + ((j)-8)*256]; \
    float4 v_; v_.x=q_.x*iv; v_.y=q_.y*iv; v_.z=q_.z*iv; v_.w=q_.w*iv; \
    *(float4*)&Et[(size_t)rk*FEAT + lane4] = v_; \
  }
  FORJ8H(WETQ)
#undef WETQ
#undef ROT_PP
#undef ROT_PQ
#undef ROT_QP
#undef ROT_QQ
#undef ROTG
#undef NRMP
#undef NRMQ
#undef RP
#undef WP
#undef RQ
#undef WQ
#undef FORJ8L
#undef FORJ8H
}

// ---------------- B[c] = EtS (256x256, sorted) @ centered_gathered (256 x n_c) ----------------
__global__ __launch_bounds__(256) void k_bmat(float* ws){
  __shared__ float Ae[256][68];   // [f][k-local]
  __shared__ float Bc[256][68];   // [f][j-local]
  int c = blockIdx.z;
  int n = ((int*)(ws+OFF_CNT))[c];
  int j0 = blockIdx.x*64;
  if (j0 >= n) return;            // block-uniform
  int kb = blockIdx.y*64;
  const float* featT = ws + OFF_FEATT;
  const int* idx = (const int*)(ws + OFF_IDX) + (size_t)c*HWPX;
  const float* miu = ws + OFF_MIU + (size_t)c*FEAT;
  const float* Ets = ws + OFF_ETS + (size_t)c*FEAT*FEAT;
  float* Bg = ws + OFF_B + (size_t)c*FEAT*BCAP;
  int t = threadIdx.x;
  int l4 = t >> 2, sgf = (t & 3)*64;
  // stage Ae
  {
    const float* Erow = Ets + (size_t)(kb+l4)*FEAT + sgf;
    for (int f=0; f<64; f+=4){
      float4 v = *(const float4*)&Erow[f];
      Ae[sgf+f+0][l4] = v.x; Ae[sgf+f+1][l4] = v.y;
      Ae[sgf+f+2][l4] = v.z; Ae[sgf+f+3][l4] = v.w;
    }
  }
  // stage Bc (centered gathered columns)
  {
    int jg = j0 + l4;
    if (jg < n){
      const float* Frow = featT + (size_t)idx[jg]*FEAT + sgf;
      const float* mp = miu + sgf;
      for (int f=0; f<64; f+=4){
        float4 v = *(const float4*)&Frow[f];
        Bc[sgf+f+0][l4] = v.x - mp[f+0];
        Bc[sgf+f+1][l4] = v.y - mp[f+1];
        Bc[sgf+f+2][l4] = v.z - mp[f+2];
        Bc[sgf+f+3][l4] = v.w - mp[f+3];
      }
    } else {
      for (int f=0; f<64; f++) Bc[sgf+f][l4] = 0.f;
    }
  }
  __syncthreads();
  int ti = t & 15, tj = t >> 4;   // ti: k-sub, tj: j-sub
  float acc[4][4] = {};
  for (int f=0; f<FEAT; f+=4){
    #pragma unroll
    for (int ff=0; ff<4; ff++){
      float4 av = *(const float4*)&Ae[f+ff][ti*4];
      float4 bv = *(const float4*)&Bc[f+ff][tj*4];
      float aa[4] = {av.x,av.y,av.z,av.w};
      float bb[4] = {bv.x,bv.y,bv.z,bv.w};
      #pragma unroll
      for (int kk=0;kk<4;kk++)
        #pragma unroll
        for (int jj=0;jj<4;jj++)
          acc[kk][jj] += aa[kk]*bb[jj];
    }
  }
  #pragma unroll
  for (int kk=0; kk<4; kk++){
    float4 o; o.x=acc[kk][0]; o.y=acc[kk][1]; o.z=acc[kk][2]; o.w=acc[kk][3];
    *(float4*)&Bg[(size_t)(kb + ti*4 + kk)*BCAP + j0 + tj*4] = o;
  }
}

// ---------------- fp GEMM (pm @ B) with fused m2/m4 + per-block loss partials ----------------
__global__ __launch_bounds__(256) void k_fp(const float* __restrict__ pm, float* ws){
  __shared__ float As[256][68];   // [k][i-local]  (pm tile, transposed)
  __shared__ float Bs[256][68];   // [k][j-local]
  __shared__ float ev[256];
  __shared__ float red[64][17];
  __shared__ float m2s[64];
  __shared__ float m4s[64];
  int c = blockIdx.y;
  int i0 = blockIdx.x*64;
  int n = ((int*)(ws+OFF_CNT))[c];
  float nf = fmaxf((float)n, 1.f);
  const float* evals = ws + OFF_EVAL + (size_t)c*FEAT;
  const float* Bg = ws + OFF_B + (size_t)c*FEAT*BCAP;
  int t = threadIdx.x;
  int l4 = t >> 2;
  // stage As
  {
    int sgf = (t & 3)*64;
    int gi = i0 + l4;
    if (gi < NDIR){
      const float* row = pm + (size_t)gi*FEAT + sgf;
      for (int f=0; f<64; f+=4){
        float4 v = *(const float4*)&row[f];
        As[sgf+f+0][l4] = v.x; As[sgf+f+1][l4] = v.y;
        As[sgf+f+2][l4] = v.z; As[sgf+f+3][l4] = v.w;
      }
    } else {
      for (int f=0; f<64; f++) As[sgf+f][l4] = 0.f;
    }
  }
  if (t < 256) ev[t] = evals[t];
  int ti = t & 15, tj = t >> 4;
  float s2[4] = {0.f,0.f,0.f,0.f};
  float s4[4] = {0.f,0.f,0.f,0.f};
  int nch = (n + 63)/64;
  int sgj = (t & 3)*16;
  for (int ch=0; ch<nch; ch++){
    int j0 = ch*64;
    __syncthreads();
    for (int g=0; g<4; g++){
      int r = l4 + 64*g;
      const float* Brow = Bg + (size_t)r*BCAP + j0 + sgj;
      #pragma unroll
      for (int e=0; e<16; e+=4){
        int j = j0 + sgj + e;
        float4 v;
        if (j + 3 < n) v = *(const float4*)&Brow[e];
        else {
          v.x = (j+0<n)? Brow[e+0] : 0.f;
          v.y = (j+1<n)? Brow[e+1] : 0.f;
          v.z = (j+2<n)? Brow[e+2] : 0.f;
          v.w = (j+3<n)? Brow[e+3] : 0.f;
        }
        *(float4*)&Bs[r][sgj+e] = v;
      }
    }
    __syncthreads();
    float acc[4][4] = {};
    for (int k=0; k<FEAT; k+=4){
      #pragma unroll
      for (int kk=0; kk<4; kk++){
        float4 av = *(const float4*)&As[k+kk][ti*4];
        float4 bv = *(const float4*)&Bs[k+kk][tj*4];
        float aa[4] = {av.x,av.y,av.z,av.w};
        float bb[4] = {bv.x,bv.y,bv.z,bv.w};
        #pragma unroll
        for (int ii=0;ii<4;ii++)
          #pragma unroll
          for (int jj=0;jj<4;jj++)
            acc[ii][jj] += aa[ii]*bb[jj];
      }
    }
    #pragma unroll
    for (int ii=0;ii<4;ii++){
      #pragma unroll
      for (int jj=0;jj<4;jj++){
        float v = acc[ii][jj];
        float v2 = v*v;
        s2[ii] += v2;
        s4[ii] += v2*v2;
      }
    }
  }
  __syncthreads();
  #pragma unroll
  for (int ii=0;ii<4;ii++) red[ti*4+ii][tj] = s2[ii];
  __syncthreads();
  if (t < 64){
    float s = 0.f;
    for (int u=0;u<16;u++) s += red[t][u];
    m2s[t] = s;
  }
  __syncthreads();
  #pragma unroll
  for (int ii=0;ii<4;ii++) red[ti*4+ii][tj] = s4[ii];
  __syncthreads();
  if (t < 64){
    float s = 0.f;
    for (int u=0;u<16;u++) s += red[t][u];
    m4s[t] = s;
  }
  __syncthreads();
  if (t < 64){
    float stds = 0.f;
    for (int k=0;k<FEAT;k++){
      float a = As[k][t];
      stds += a*a*ev[k];
    }
    int i = i0 + t;
    float l2 = 0.f, lk = 0.f;
    if (i < NDIR){
      float m2 = m2s[t]/(nf*stds);
      float m4 = m4s[t]/(nf*stds*stds);
      float d2 = m2 - 1.f;
      l2 = d2*d2;
      float dk = m4 - 3.f*m2*m2;
      lk = dk*dk;
    }
    #pragma unroll
    for (int o=1;o<64;o<<=1){
      l2 += __shfl_xor(l2, o);
      lk += __shfl_xor(lk, o);
    }
    if (t == 0){
      float* lp = ws + OFF_LPART + ((size_t)c*160 + blockIdx.x)*2;
      lp[0] = l2;
      lp[1] = lk;
    }
  }
}

// ---------------- final scalar (deterministic fixed-order reduction) ----------------
__global__ __launch_bounds__(64) void k_final(float* ws, float* out){
  int t = threadIdx.x;   // one wave
  const int* cnt = (const int*)(ws + OFF_CNT);
  const float* lp = ws + OFF_LPART;
  float tot = 0.f, an = 0.f;
  for (int c=0;c<NCLS;c++){
    float s2 = 0.f, sk = 0.f;
    for (int b=t; b<NBLK_FP; b+=64){
      s2 += lp[((size_t)c*160 + b)*2 + 0];
      sk += lp[((size_t)c*160 + b)*2 + 1];
    }
    #pragma unroll
    for (int o=1;o<64;o<<=1){
      s2 += __shfl_xor(s2, o);
      sk += __shfl_xor(sk, o);
    }
    if (cnt[c] > 0){
      tot += s2/(float)NDIR + sk/(float)NDIR;
      an += 1.f;
    }
  }
  if (t == 0) out[0] = tot / fmaxf(an, 1.f);
}

extern "C" void kernel_launch(void* const* d_in, const int* in_sizes, int n_in,
                              void* d_out, int out_size, void* d_ws, size_t ws_size,
                              hipStream_t stream) {
  const float* feat = (const float*)d_in[0];
  const int*   lab  = (const int*)d_in[1];
  const float* pm   = (const float*)d_in[2];
  float* out = (float*)d_out;
  float* ws  = (float*)d_ws;

  hipLaunchKernelGGL(k_transpose, dim3(HWPX/32, FEAT/32), dim3(32,8), 0, stream, feat, ws);
  hipLaunchKernelGGL(k_index,     dim3(1),            dim3(256),     0, stream, lab, ws);
  hipLaunchKernelGGL(k_miu_part,  dim3(32),           dim3(256),     0, stream, lab, ws);
  hipLaunchKernelGGL(k_miu_fin,   dim3(1),            dim3(1024),    0, stream, ws);
  hipLaunchKernelGGL(k_cov,       dim3(16, NCLS),     dim3(256),     0, stream, ws);
  hipLaunchKernelGGL(k_jacobi,    dim3(NCLS),         dim3(1024),    0, stream, ws);
  hipLaunchKernelGGL(k_bmat,      dim3(BCAP/64, 4, NCLS), dim3(256), 0, stream, ws);
  hipLaunchKernelGGL(k_fp,        dim3(NBLK_FP, NCLS), dim3(256),    0, stream, pm, ws);
  hipLaunchKernelGGL(k_final,     dim3(1),            dim3(64),      0, stream, ws, out);
}

// Round 9
// 10321.594 us; speedup vs baseline: 4.2932x; 1.3629x over previous
//
#include <hip/hip_runtime.h>
#include <cstdint>
#include <cstddef>

#define FEAT 256
#define HWPX 16384
#define NDIR 10000
#define NCLS 4          // classes 1..4
#define BCAP 4096       // per-class column capacity for B (n_c ~ 3277)
#define NSWO 7          // outer block-Jacobi sweeps (fixed, deterministic; 7*31 % 31 == 0)
#define JTOL 4e-12f     // skip rotation if d^2 <= na*nb*JTOL
#define NBLK_FP 157     // ceil(NDIR/64)

// ---- workspace layout (element offsets; 4B elements) ----
static const size_t OFF_FEATT = 0;                                // 16384*256 f32
static const size_t OFF_IDX   = OFF_FEATT + (size_t)HWPX*FEAT;    // 4*16384 int
static const size_t OFF_CNT   = OFF_IDX + (size_t)NCLS*HWPX;      // 4 int (+pad)
static const size_t OFF_MIU   = OFF_CNT + 64;                     // 4*256 f32
static const size_t OFF_MIUP  = OFF_MIU + (size_t)NCLS*FEAT;      // 32*4*256 f32 partials
static const size_t OFF_G     = OFF_MIUP + (size_t)32*NCLS*FEAT;  // 4*65536 f32
static const size_t OFF_ETS   = OFF_G + (size_t)NCLS*FEAT*FEAT;   // 4*65536 f32
static const size_t OFF_EVAL  = OFF_ETS + (size_t)NCLS*FEAT*FEAT; // 4*256 f32
static const size_t OFF_LPART = OFF_EVAL + (size_t)NCLS*FEAT;     // 4*160*2 f32 per-block partials
static const size_t OFF_B     = OFF_LPART + (size_t)NCLS*160*2;   // 4*256*BCAP f32
static const size_t OFF_XCH   = OFF_B + (size_t)NCLS*FEAT*BCAP;   // 4*2*32*2048 f32 transit
// total ~ 39 MB

// 64-lane sum, deterministic fixed order, result uniform.
// 4 DPP row-rotate adds (16-lane allreduce) + 4 readlane + 3 adds.
__device__ __forceinline__ float wsum64(float v){
  int x;
  x = __builtin_amdgcn_update_dpp(0, __float_as_int(v), 0x121, 0xF, 0xF, false); v += __int_as_float(x); // row_ror:1
  x = __builtin_amdgcn_update_dpp(0, __float_as_int(v), 0x122, 0xF, 0xF, false); v += __int_as_float(x); // row_ror:2
  x = __builtin_amdgcn_update_dpp(0, __float_as_int(v), 0x124, 0xF, 0xF, false); v += __int_as_float(x); // row_ror:4
  x = __builtin_amdgcn_update_dpp(0, __float_as_int(v), 0x128, 0xF, 0xF, false); v += __int_as_float(x); // row_ror:8
  float a = __int_as_float(__builtin_amdgcn_readlane(__float_as_int(v), 0));
  float b = __int_as_float(__builtin_amdgcn_readlane(__float_as_int(v), 16));
  float c = __int_as_float(__builtin_amdgcn_readlane(__float_as_int(v), 32));
  float d = __int_as_float(__builtin_amdgcn_readlane(__float_as_int(v), 48));
  return (a + b) + (c + d);
}

// ---------------- transpose feat (256 x 16384) -> featT (16384 x 256) ----------------
__global__ __launch_bounds__(256) void k_transpose(const float* __restrict__ feat, float* __restrict__ ws){
  __shared__ float tile[32][33];
  float* featT = ws + OFF_FEATT;
  int j0 = blockIdx.x*32, f0 = blockIdx.y*32;
  int tx = threadIdx.x, ty = threadIdx.y; // (32, 8)
  #pragma unroll
  for (int r=0;r<4;r++){
    int f = f0 + ty + r*8;
    tile[ty+r*8][tx] = feat[(size_t)f*HWPX + j0 + tx];
  }
  __syncthreads();
  #pragma unroll
  for (int r=0;r<4;r++){
    int j = j0 + ty + r*8;
    featT[(size_t)j*FEAT + f0 + tx] = tile[tx][ty+r*8];
  }
}

// ---------------- build compacted per-class index lists + counts ----------------
__global__ __launch_bounds__(256) void k_index(const int* __restrict__ lab, float* ws){
  __shared__ int sc[256];
  int* idx = (int*)(ws + OFF_IDX);
  int* cnt = (int*)(ws + OFF_CNT);
  int t = threadIdx.x;
  int base = t*64;
  for (int c=1;c<=NCLS;c++){
    __syncthreads();
    int m = 0;
    for (int k=0;k<64;k++) m += (lab[base+k]==c) ? 1 : 0;
    sc[t] = m;
    __syncthreads();
    for (int off=1; off<256; off<<=1){
      int v = (t>=off)? sc[t-off] : 0;
      __syncthreads();
      sc[t] += v;
      __syncthreads();
    }
    int pos = sc[t] - m;
    if (t==255) cnt[c-1] = sc[255];
    int* ic = idx + (size_t)(c-1)*HWPX;
    for (int k=0;k<64;k++){
      if (lab[base+k]==c) ic[pos++] = base+k;
    }
  }
}

// ---------------- per-class feature-sum partials (deterministic, no atomics) ----------------
__global__ __launch_bounds__(256) void k_miu_part(const int* __restrict__ lab, float* ws){
  const float* featT = ws + OFF_FEATT;
  float* part = ws + OFF_MIUP;
  int f = threadIdx.x;
  int b = blockIdx.x;
  int j0 = b*512;
  float a0=0.f,a1=0.f,a2=0.f,a3=0.f;
  for (int j=j0;j<j0+512;j++){
    float v = featT[(size_t)j*FEAT + f];
    int c = lab[j];
    a0 += (c==1)? v : 0.f;
    a1 += (c==2)? v : 0.f;
    a2 += (c==3)? v : 0.f;
    a3 += (c==4)? v : 0.f;
  }
  float* pb = part + (size_t)b*NCLS*FEAT;
  pb[0*FEAT+f] = a0;
  pb[1*FEAT+f] = a1;
  pb[2*FEAT+f] = a2;
  pb[3*FEAT+f] = a3;
}

__global__ __launch_bounds__(1024) void k_miu_fin(float* ws){
  int t = threadIdx.x;            // 0..1023 = c*FEAT+f
  int c = t / FEAT;
  const float* part = ws + OFF_MIUP;
  float s = 0.f;
  for (int b=0;b<32;b++) s += part[(size_t)b*NCLS*FEAT + t];   // fixed order
  int n = ((int*)(ws+OFF_CNT))[c];
  float nf = fmaxf((float)n, 1.f);
  ws[OFF_MIU + t] = s / nf;
}

// ---------------- cov per class (64x64 tiles): G = m2mat/n - miu miu^T + eps I ----------------
__global__ __launch_bounds__(256) void k_cov(float* ws){
  __shared__ float Xa[32][68];
  __shared__ float Xb[32][68];
  const float* featT = ws + OFF_FEATT;
  int c = blockIdx.y;
  const int* idx = (const int*)(ws + OFF_IDX) + (size_t)c*HWPX;
  int n = ((int*)(ws+OFF_CNT))[c];
  float nf = fmaxf((float)n,1.f);
  const float* miu = ws + OFF_MIU + (size_t)c*FEAT;
  float* G = ws + OFF_G + (size_t)c*FEAT*FEAT;
  int fb = (blockIdx.x & 3)*64, gb = (blockIdx.x >> 2)*64;
  int t = threadIdx.x;
  int ti = t & 15, tj = t >> 4;
  float acc[4][4] = {};
  int jr = t >> 3;         // 0..31
  int s8 = (t & 7) * 8;    // 0..56
  int nch = (n + 31)/32;
  for (int ch=0; ch<nch; ch++){
    int jg = ch*32 + jr;
    __syncthreads();
    if (jg < n){
      int jx = idx[jg];
      const float* row = featT + (size_t)jx*FEAT;
      #pragma unroll
      for (int k=0;k<8;k++){ Xa[jr][s8+k] = row[fb+s8+k]; Xb[jr][s8+k] = row[gb+s8+k]; }
    } else {
      #pragma unroll
      for (int k=0;k<8;k++){ Xa[jr][s8+k] = 0.f; Xb[jr][s8+k] = 0.f; }
    }
    __syncthreads();
    for (int jj=0;jj<32;jj++){
      float4 av = *(const float4*)&Xa[jj][ti*4];
      float4 bv = *(const float4*)&Xb[jj][tj*4];
      float aa[4] = {av.x,av.y,av.z,av.w};
      float bb[4] = {bv.x,bv.y,bv.z,bv.w};
      #pragma unroll
      for (int ii=0; ii<4; ii++)
        #pragma unroll
        for (int j2=0; j2<4; j2++)
          acc[ii][j2] += aa[ii]*bb[j2];
    }
  }
  float eps = fminf(fmaxf(1e-5f/nf, 1e-8f), 1e-5f);
  #pragma unroll
  for (int ii=0; ii<4; ii++){
    #pragma unroll
    for (int j2=0; j2<4; j2++){
      int f = fb + ti*4 + ii, g = gb + tj*4 + j2;
      float v = acc[ii][j2]/nf - miu[f]*miu[g] + ((f==g)? eps : 0.f);
      G[(size_t)g*FEAT + f] = v;   // column-major, col g
    }
  }
}

// ---------------- one-sided BLOCK Jacobi, P-in-registers / Q-in-LDS, LEAN schedule ----------------
// 32 groups of 8 columns; wave w owns a group-pair. Per round: 64 CROSS pairs
// (8 micro-rounds of 8 disjoint (i, 8+((i+s)&7))); every 4th round additionally
// the 56 intra-group pairs (7-round circle per group). Cross coverage per sweep
// is identical to the full 120-pair tournament; intra pairs still get 54 sweeps
// over the run. Rotation arithmetic/wsum64/transit are BIT-IDENTICAL to R8 —
// only the rotation set changed.
__global__ void
__attribute__((amdgpu_flat_work_group_size(1024,1024), amdgpu_waves_per_eu(4,4)))
k_jacobi(float* ws){
  __shared__ float QS[17*2048];   // 17 slots x (8 cols x 256 floats) = 139264 B
  __shared__ float colsq[256];
  __shared__ int srt[256];
  __shared__ int inv_[256];
  int c = blockIdx.x;
  float* G = ws + OFF_G + (size_t)c*FEAT*FEAT;
  float* X = ws + OFF_XCH + (size_t)c*2*32*2048;
  int t = threadIdx.x;
  int lane = t & 63;
  int lane4 = lane*4;
  int w = t >> 6;             // wave 0..15

#define FORJ8L(M) M(0) M(1) M(2) M(3) M(4) M(5) M(6) M(7)
#define FORJ8H(M) M(8) M(9) M(10) M(11) M(12) M(13) M(14) M(15)

  // P columns (group pg), named scalars
#define DECL(j) float C##j##x, C##j##y, C##j##z, C##j##w;
  FORJ8L(DECL)
#undef DECL
  float n0,n1,n2,n3,n4,n5,n6,n7,n8,n9,n10,n11,n12,n13,n14,n15;

  int pg = (w==0)? 31 : w;        // initial (and final) group ids
  int qg = (w==0)? 0  : 31 - w;

  int qslot = w;                  // this wave's Q slot
  int freeslot = 16;              // the idle slot (wave 1 writes into it each round)
  int qbase = qslot*2048 + lane4;

  // initial load: P -> regs, Q -> own LDS slot
#define LDP(j) { float4 v_ = *(const float4*)&G[(size_t)(pg*8+(j))*FEAT + lane4]; \
                 C##j##x=v_.x; C##j##y=v_.y; C##j##z=v_.z; C##j##w=v_.w; }
  FORJ8L(LDP)
#undef LDP
#define LDQ(j) { float4 v_ = *(const float4*)&G[(size_t)(qg*8+((j)-8))*FEAT + lane4]; \
                 *(float4*)&QS[qbase + ((j)-8)*256] = v_; }
  FORJ8H(LDQ)
#undef LDQ

  // storage accessors (global column id 0..15; 0..7 = P regs, 8..15 = Q LDS)
#define RP(g,ax,ay,az,aw) ax=C##g##x; ay=C##g##y; az=C##g##z; aw=C##g##w;
#define WP(g,ax,ay,az,aw) C##g##x=ax; C##g##y=ay; C##g##z=az; C##g##w=aw;
#define RQ(g,ax,ay,az,aw) { const float4 q_ = *(const float4*)&QS[qbase + ((g)-8)*256]; \
                            ax=q_.x; ay=q_.y; az=q_.z; aw=q_.w; }
#define WQ(g,ax,ay,az,aw) { float4 q_; q_.x=ax; q_.y=ay; q_.z=az; q_.w=aw; \
                            *(float4*)&QS[qbase + ((g)-8)*256] = q_; }

#define NRMP(j) n##j = wsum64(C##j##x*C##j##x + C##j##y*C##j##y + C##j##z*C##j##z + C##j##w*C##j##w);
#define NRMQ(j) { float ax,ay,az,aw; RQ(j,ax,ay,az,aw) \
                  n##j = wsum64(ax*ax + ay*ay + az*az + aw*aw); }

#define ROTG(LA,SA,ga,LB,SB,gb) { \
    float ax,ay,az,aw,bx,by,bz,bw; \
    LA(ga,ax,ay,az,aw) \
    LB(gb,bx,by,bz,bw) \
    float dp = ax*bx + ay*by + az*bz + aw*bw; \
    float d = wsum64(dp); \
    float na = n##ga, nb = n##gb; \
    if (d*d > na*nb*JTOL){ \
      float tau = (nb - na) * 0.5f * __builtin_amdgcn_rcpf(d); \
      float tt = copysignf(__builtin_amdgcn_rcpf(fabsf(tau) + __builtin_amdgcn_sqrtf(1.f + tau*tau)), tau); \
      float cc = __builtin_amdgcn_rsqf(1.f + tt*tt); \
      float sn = tt*cc; \
      float x_; \
      x_ = ax; ax = cc*x_ - sn*bx; bx = sn*x_ + cc*bx; \
      x_ = ay; ay = cc*x_ - sn*by; by = sn*x_ + cc*by; \
      x_ = az; az = cc*x_ - sn*bz; bz = sn*x_ + cc*bz; \
      x_ = aw; aw = cc*x_ - sn*bw; bw = sn*x_ + cc*bw; \
      float cc2 = cc*cc, sn2 = sn*sn, csd = 2.f*cc*sn*d; \
      n##ga = cc2*na - csd + sn2*nb; \
      n##gb = sn2*na + csd + cc2*nb; \
      SA(ga,ax,ay,az,aw) \
      SB(gb,bx,by,bz,bw) \
    } \
  }
#define ROT_PP(a,b) ROTG(RP,WP,a,RP,WP,b)
#define ROT_PQ(a,b) ROTG(RP,WP,a,RQ,WQ,b)
#define ROT_QQ(a,b) ROTG(RQ,WQ,a,RQ,WQ,b)

  for (int R=0; R<NSWO*31; R++){
    // exact column norms (refreshed each outer round; uniform across lanes)
    NRMP(0) NRMP(1) NRMP(2) NRMP(3) NRMP(4) NRMP(5) NRMP(6) NRMP(7)
    NRMQ(8) NRMQ(9) NRMQ(10) NRMQ(11) NRMQ(12) NRMQ(13) NRMQ(14) NRMQ(15)
    // ---- cross pairs: 8 micro-rounds of 8 disjoint (i, 8+((i+s)&7)) ----
    ROT_PQ(0,8)  ROT_PQ(1,9)  ROT_PQ(2,10) ROT_PQ(3,11) ROT_PQ(4,12) ROT_PQ(5,13) ROT_PQ(6,14) ROT_PQ(7,15)
    ROT_PQ(0,9)  ROT_PQ(1,10) ROT_PQ(2,11) ROT_PQ(3,12) ROT_PQ(4,13) ROT_PQ(5,14) ROT_PQ(6,15) ROT_PQ(7,8)
    ROT_PQ(0,10) ROT_PQ(1,11) ROT_PQ(2,12) ROT_PQ(3,13) ROT_PQ(4,14) ROT_PQ(5,15) ROT_PQ(6,8)  ROT_PQ(7,9)
    ROT_PQ(0,11) ROT_PQ(1,12) ROT_PQ(2,13) ROT_PQ(3,14) ROT_PQ(4,15) ROT_PQ(5,8)  ROT_PQ(6,9)  ROT_PQ(7,10)
    ROT_PQ(0,12) ROT_PQ(1,13) ROT_PQ(2,14) ROT_PQ(3,15) ROT_PQ(4,8)  ROT_PQ(5,9)  ROT_PQ(6,10) ROT_PQ(7,11)
    ROT_PQ(0,13) ROT_PQ(1,14) ROT_PQ(2,15) ROT_PQ(3,8)  ROT_PQ(4,9)  ROT_PQ(5,10) ROT_PQ(6,11) ROT_PQ(7,12)
    ROT_PQ(0,14) ROT_PQ(1,15) ROT_PQ(2,8)  ROT_PQ(3,9)  ROT_PQ(4,10) ROT_PQ(5,11) ROT_PQ(6,12) ROT_PQ(7,13)
    ROT_PQ(0,15) ROT_PQ(1,8)  ROT_PQ(2,9)  ROT_PQ(3,10) ROT_PQ(4,11) ROT_PQ(5,12) ROT_PQ(6,13) ROT_PQ(7,14)
    // ---- intra-group pairs every 4th round (7-round circle per group) ----
    if ((R & 3) == 3){
      ROT_PP(7,0) ROT_PP(1,6) ROT_PP(2,5) ROT_PP(3,4)  ROT_QQ(15,8)  ROT_QQ(9,14)  ROT_QQ(10,13) ROT_QQ(11,12)
      ROT_PP(7,1) ROT_PP(2,0) ROT_PP(3,6) ROT_PP(4,5)  ROT_QQ(15,9)  ROT_QQ(10,8)  ROT_QQ(11,14) ROT_QQ(12,13)
      ROT_PP(7,2) ROT_PP(3,1) ROT_PP(4,0) ROT_PP(5,6)  ROT_QQ(15,10) ROT_QQ(11,9)  ROT_QQ(12,8)  ROT_QQ(13,14)
      ROT_PP(7,3) ROT_PP(4,2) ROT_PP(5,1) ROT_PP(6,0)  ROT_QQ(15,11) ROT_QQ(12,10) ROT_QQ(13,9)  ROT_QQ(14,8)
      ROT_PP(7,4) ROT_PP(5,3) ROT_PP(6,2) ROT_PP(0,1)  ROT_QQ(15,12) ROT_QQ(13,11) ROT_QQ(14,10) ROT_QQ(8,9)
      ROT_PP(7,5) ROT_PP(6,4) ROT_PP(0,3) ROT_PP(1,2)  ROT_QQ(15,13) ROT_QQ(14,12) ROT_QQ(8,11)  ROT_QQ(9,10)
      ROT_PP(7,6) ROT_PP(0,5) ROT_PP(1,4) ROT_PP(2,3)  ROT_QQ(15,14) ROT_QQ(8,13)  ROT_QQ(9,12)  ROT_QQ(10,11)
    }

    // ---- transit: P via global parity buffer; Q via LDS slot rotation ----
    int par = R & 1;
    float* XB = X + (size_t)par*32*2048;
    if (w >= 2){
#define STP(j) { float4 v_; v_.x=C##j##x; v_.y=C##j##y; v_.z=C##j##z; v_.w=C##j##w; \
                 *(float4*)&XB[(size_t)w*2048 + (j)*256 + lane4] = v_; }
      FORJ8L(STP)
#undef STP
    }
    if (w == 1){
      // oldP_1 becomes wave 0's newQ: write into the free LDS slot
      int fb_ = freeslot*2048 + lane4;
#define STF(j) { float4 v_; v_.x=C##j##x; v_.y=C##j##y; v_.z=C##j##z; v_.w=C##j##w; \
                 *(float4*)&QS[fb_ + (j)*256] = v_; }
      FORJ8L(STF)
#undef STF
    }
    if (w == 15){
      // newP_15 = own oldQ (read own slot pre-barrier; safe, wave-private)
#define LPQ(j) { const float4 q_ = *(const float4*)&QS[qbase + (j)*256]; \
                 C##j##x=q_.x; C##j##y=q_.y; C##j##z=q_.z; C##j##w=q_.w; }
      FORJ8L(LPQ)
#undef LPQ
    }
    __syncthreads();
    if (w >= 1 && w <= 14){
#define LP(j) { float4 v_ = *(const float4*)&XB[(size_t)(w+1)*2048 + (j)*256 + lane4]; \
                C##j##x=v_.x; C##j##y=v_.y; C##j##z=v_.z; C##j##w=v_.w; }
      FORJ8L(LP)                                                   // newP_w = oldP_{w+1}
#undef LP
    }
    // slot rotation: newQ_w = oldQ_{w-1}; wave0 adopts the just-written free slot
    qslot += 16; if (qslot >= 17) qslot -= 17;
    freeslot += 16; if (freeslot >= 17) freeslot -= 17;
    qbase = qslot*2048 + lane4;
  }

  // ---- extraction: exact norms, global rank-sort, normalized rows out ----
  NRMP(0) NRMP(1) NRMP(2) NRMP(3) NRMP(4) NRMP(5) NRMP(6) NRMP(7)
  NRMQ(8) NRMQ(9) NRMQ(10) NRMQ(11) NRMQ(12) NRMQ(13) NRMQ(14) NRMQ(15)
#define WCS(j) if (lane == (j)) colsq[((j)<8)? (pg*8+(j)) : (qg*8+(j)-8)] = n##j;
  FORJ8L(WCS) FORJ8H(WCS)
#undef WCS
  __syncthreads();
  if (t < 256){
    float my = colsq[t];
    int rk = 0;
    for (int u=0; u<256; u++){
      float cu = colsq[u];
      rk += ((cu > my) || (cu == my && u < t)) ? 1 : 0;
    }
    srt[rk] = t;
  }
  __syncthreads();
  float* evals = ws + OFF_EVAL + (size_t)c*FEAT;
  if (t < 256){
    evals[t] = sqrtf(colsq[srt[t]]);
    inv_[srt[t]] = t;
  }
  __syncthreads();
  float* Et = ws + OFF_ETS + (size_t)c*FEAT*FEAT;
#define WETP(j) { \
    int rk = inv_[pg*8+(j)]; \
    float iv = 1.f / sqrtf(n##j); \
    float4 v_; v_.x=C##j##x*iv; v_.y=C##j##y*iv; v_.z=C##j##z*iv; v_.w=C##j##w*iv; \
    *(float4*)&Et[(size_t)rk*FEAT + lane4] = v_; \
  }
  FORJ8L(WETP)
#undef WETP
#define WETQ(j) { \
    int rk = inv_[qg*8+(j)-8]; \
    float iv = 1.f / sqrtf(n##j); \
    const float4 q_ = *(const float4*)&QS[qbase + ((j)-8)*256]; \
    float4 v_; v_.x=q_.x*iv; v_.y=q_.y*iv; v_.z=q_.z*iv; v_.w=q_.w*iv; \
    *(float4*)&Et[(size_t)rk*FEAT + lane4] = v_; \
  }
  FORJ8H(WETQ)
#undef WETQ
#undef ROT_PP
#undef ROT_PQ
#undef ROT_QQ
#undef ROTG
#undef NRMP
#undef NRMQ
#undef RP
#undef WP
#undef RQ
#undef WQ
#undef FORJ8L
#undef FORJ8H
}

// ---------------- B[c] = EtS (256x256, sorted) @ centered_gathered (256 x n_c) ----------------
__global__ __launch_bounds__(256) void k_bmat(float* ws){
  __shared__ float Ae[256][68];   // [f][k-local]
  __shared__ float Bc[256][68];   // [f][j-local]
  int c = blockIdx.z;
  int n = ((int*)(ws+OFF_CNT))[c];
  int j0 = blockIdx.x*64;
  if (j0 >= n) return;            // block-uniform
  int kb = blockIdx.y*64;
  const float* featT = ws + OFF_FEATT;
  const int* idx = (const int*)(ws + OFF_IDX) + (size_t)c*HWPX;
  const float* miu = ws + OFF_MIU + (size_t)c*FEAT;
  const float* Ets = ws + OFF_ETS + (size_t)c*FEAT*FEAT;
  float* Bg = ws + OFF_B + (size_t)c*FEAT*BCAP;
  int t = threadIdx.x;
  int l4 = t >> 2, sgf = (t & 3)*64;
  // stage Ae
  {
    const float* Erow = Ets + (size_t)(kb+l4)*FEAT + sgf;
    for (int f=0; f<64; f+=4){
      float4 v = *(const float4*)&Erow[f];
      Ae[sgf+f+0][l4] = v.x; Ae[sgf+f+1][l4] = v.y;
      Ae[sgf+f+2][l4] = v.z; Ae[sgf+f+3][l4] = v.w;
    }
  }
  // stage Bc (centered gathered columns)
  {
    int jg = j0 + l4;
    if (jg < n){
      const float* Frow = featT + (size_t)idx[jg]*FEAT + sgf;
      const float* mp = miu + sgf;
      for (int f=0; f<64; f+=4){
        float4 v = *(const float4*)&Frow[f];
        Bc[sgf+f+0][l4] = v.x - mp[f+0];
        Bc[sgf+f+1][l4] = v.y - mp[f+1];
        Bc[sgf+f+2][l4] = v.z - mp[f+2];
        Bc[sgf+f+3][l4] = v.w - mp[f+3];
      }
    } else {
      for (int f=0; f<64; f++) Bc[sgf+f][l4] = 0.f;
    }
  }
  __syncthreads();
  int ti = t & 15, tj = t >> 4;   // ti: k-sub, tj: j-sub
  float acc[4][4] = {};
  for (int f=0; f<FEAT; f+=4){
    #pragma unroll
    for (int ff=0; ff<4; ff++){
      float4 av = *(const float4*)&Ae[f+ff][ti*4];
      float4 bv = *(const float4*)&Bc[f+ff][tj*4];
      float aa[4] = {av.x,av.y,av.z,av.w};
      float bb[4] = {bv.x,bv.y,bv.z,bv.w};
      #pragma unroll
      for (int kk=0;kk<4;kk++)
        #pragma unroll
        for (int jj=0;jj<4;jj++)
          acc[kk][jj] += aa[kk]*bb[jj];
    }
  }
  #pragma unroll
  for (int kk=0; kk<4; kk++){
    float4 o; o.x=acc[kk][0]; o.y=acc[kk][1]; o.z=acc[kk][2]; o.w=acc[kk][3];
    *(float4*)&Bg[(size_t)(kb + ti*4 + kk)*BCAP + j0 + tj*4] = o;
  }
}

// ---------------- fp GEMM (pm @ B) with fused m2/m4 + per-block loss partials ----------------
__global__ __launch_bounds__(256) void k_fp(const float* __restrict__ pm, float* ws){
  __shared__ float As[256][68];   // [k][i-local]  (pm tile, transposed)
  __shared__ float Bs[256][68];   // [k][j-local]
  __shared__ float ev[256];
  __shared__ float red[64][17];
  __shared__ float m2s[64];
  __shared__ float m4s[64];
  int c = blockIdx.y;
  int i0 = blockIdx.x*64;
  int n = ((int*)(ws+OFF_CNT))[c];
  float nf = fmaxf((float)n, 1.f);
  const float* evals = ws + OFF_EVAL + (size_t)c*FEAT;
  const float* Bg = ws + OFF_B + (size_t)c*FEAT*BCAP;
  int t = threadIdx.x;
  int l4 = t >> 2;
  // stage As
  {
    int sgf = (t & 3)*64;
    int gi = i0 + l4;
    if (gi < NDIR){
      const float* row = pm + (size_t)gi*FEAT + sgf;
      for (int f=0; f<64; f+=4){
        float4 v = *(const float4*)&row[f];
        As[sgf+f+0][l4] = v.x; As[sgf+f+1][l4] = v.y;
        As[sgf+f+2][l4] = v.z; As[sgf+f+3][l4] = v.w;
      }
    } else {
      for (int f=0; f<64; f++) As[sgf+f][l4] = 0.f;
    }
  }
  if (t < 256) ev[t] = evals[t];
  int ti = t & 15, tj = t >> 4;
  float s2[4] = {0.f,0.f,0.f,0.f};
  float s4[4] = {0.f,0.f,0.f,0.f};
  int nch = (n + 63)/64;
  int sgj = (t & 3)*16;
  for (int ch=0; ch<nch; ch++){
    int j0 = ch*64;
    __syncthreads();
    for (int g=0; g<4; g++){
      int r = l4 + 64*g;
      const float* Brow = Bg + (size_t)r*BCAP + j0 + sgj;
      #pragma unroll
      for (int e=0; e<16; e+=4){
        int j = j0 + sgj + e;
        float4 v;
        if (j + 3 < n) v = *(const float4*)&Brow[e];
        else {
          v.x = (j+0<n)? Brow[e+0] : 0.f;
          v.y = (j+1<n)? Brow[e+1] : 0.f;
          v.z = (j+2<n)? Brow[e+2] : 0.f;
          v.w = (j+3<n)? Brow[e+3] : 0.f;
        }
        *(float4*)&Bs[r][sgj+e] = v;
      }
    }
    __syncthreads();
    float acc[4][4] = {};
    for (int k=0; k<FEAT; k+=4){
      #pragma unroll
      for (int kk=0; kk<4; kk++){
        float4 av = *(const float4*)&As[k+kk][ti*4];
        float4 bv = *(const float4*)&Bs[k+kk][tj*4];
        float aa[4] = {av.x,av.y,av.z,av.w};
        float bb[4] = {bv.x,bv.y,bv.z,bv.w};
        #pragma unroll
        for (int ii=0;ii<4;ii++)
          #pragma unroll
          for (int jj=0;jj<4;jj++)
            acc[ii][jj] += aa[ii]*bb[jj];
      }
    }
    #pragma unroll
    for (int ii=0;ii<4;ii++){
      #pragma unroll
      for (int jj=0;jj<4;jj++){
        float v = acc[ii][jj];
        float v2 = v*v;
        s2[ii] += v2;
        s4[ii] += v2*v2;
      }
    }
  }
  __syncthreads();
  #pragma unroll
  for (int ii=0;ii<4;ii++) red[ti*4+ii][tj] = s2[ii];
  __syncthreads();
  if (t < 64){
    float s = 0.f;
    for (int u=0;u<16;u++) s += red[t][u];
    m2s[t] = s;
  }
  __syncthreads();
  #pragma unroll
  for (int ii=0;ii<4;ii++) red[ti*4+ii][tj] = s4[ii];
  __syncthreads();
  if (t < 64){
    float s = 0.f;
    for (int u=0;u<16;u++) s += red[t][u];
    m4s[t] = s;
  }
  __syncthreads();
  if (t < 64){
    float stds = 0.f;
    for (int k=0;k<FEAT;k++){
      float a = As[k][t];
      stds += a*a*ev[k];
    }
    int i = i0 + t;
    float l2 = 0.f, lk = 0.f;
    if (i < NDIR){
      float m2 = m2s[t]/(nf*stds);
      float m4 = m4s[t]/(nf*stds*stds);
      float d2 = m2 - 1.f;
      l2 = d2*d2;
      float dk = m4 - 3.f*m2*m2;
      lk = dk*dk;
    }
    #pragma unroll
    for (int o=1;o<64;o<<=1){
      l2 += __shfl_xor(l2, o);
      lk += __shfl_xor(lk, o);
    }
    if (t == 0){
      float* lp = ws + OFF_LPART + ((size_t)c*160 + blockIdx.x)*2;
      lp[0] = l2;
      lp[1] = lk;
    }
  }
}

// ---------------- final scalar (deterministic fixed-order reduction) ----------------
__global__ __launch_bounds__(64) void k_final(float* ws, float* out){
  int t = threadIdx.x;   // one wave
  const int* cnt = (const int*)(ws + OFF_CNT);
  const float* lp = ws + OFF_LPART;
  float tot = 0.f, an = 0.f;
  for (int c=0;c<NCLS;c++){
    float s2 = 0.f, sk = 0.f;
    for (int b=t; b<NBLK_FP; b+=64){
      s2 += lp[((size_t)c*160 + b)*2 + 0];
      sk += lp[((size_t)c*160 + b)*2 + 1];
    }
    #pragma unroll
    for (int o=1;o<64;o<<=1){
      s2 += __shfl_xor(s2, o);
      sk += __shfl_xor(sk, o);
    }
    if (cnt[c] > 0){
      tot += s2/(float)NDIR + sk/(float)NDIR;
      an += 1.f;
    }
  }
  if (t == 0) out[0] = tot / fmaxf(an, 1.f);
}

extern "C" void kernel_launch(void* const* d_in, const int* in_sizes, int n_in,
                              void* d_out, int out_size, void* d_ws, size_t ws_size,
                              hipStream_t stream) {
  const float* feat = (const float*)d_in[0];
  const int*   lab  = (const int*)d_in[1];
  const float* pm   = (const float*)d_in[2];
  float* out = (float*)d_out;
  float* ws  = (float*)d_ws;

  hipLaunchKernelGGL(k_transpose, dim3(HWPX/32, FEAT/32), dim3(32,8), 0, stream, feat, ws);
  hipLaunchKernelGGL(k_index,     dim3(1),            dim3(256),     0, stream, lab, ws);
  hipLaunchKernelGGL(k_miu_part,  dim3(32),           dim3(256),     0, stream, lab, ws);
  hipLaunchKernelGGL(k_miu_fin,   dim3(1),            dim3(1024),    0, stream, ws);
  hipLaunchKernelGGL(k_cov,       dim3(16, NCLS),     dim3(256),     0, stream, ws);
  hipLaunchKernelGGL(k_jacobi,    dim3(NCLS),         dim3(1024),    0, stream, ws);
  hipLaunchKernelGGL(k_bmat,      dim3(BCAP/64, 4, NCLS), dim3(256), 0, stream, ws);
  hipLaunchKernelGGL(k_fp,        dim3(NBLK_FP, NCLS), dim3(256),    0, stream, pm, ws);
  hipLaunchKernelGGL(k_final,     dim3(1),            dim3(64),      0, stream, ws, out);
}